// Round 1
// baseline (401.460 us; speedup 1.0000x reference)
//
#include <hip/hip_runtime.h>

typedef __bf16 bf16;
typedef __bf16 bf16x8 __attribute__((ext_vector_type(8)));
typedef __bf16 bf16x4 __attribute__((ext_vector_type(4)));
typedef float f32x4 __attribute__((ext_vector_type(4)));

#define MFMA16(a, b, c) __builtin_amdgcn_mfma_f32_16x16x32_bf16(a, b, c, 0, 0, 0)

// async global -> LDS, 16 B per lane. lds ptr must be WAVE-UNIFORM base;
// HW places lane i at base + i*16.
#define GLL(lds, g)                                                    \
  __builtin_amdgcn_global_load_lds(                                    \
      (const __attribute__((address_space(1))) void*)(g),              \
      (__attribute__((address_space(3))) void*)(lds), 16, 0, 0)

// ---------------- fused prologue ----------------
// Phase order = dispatch order; transposes (longest per-block latency) first
// so the streaming copy fills the tail instead of LDS-round-trip blocks.
// blocks [0,2560):    wqkv transpose, 64x64 tiles (40 k-tiles x 64 n-tiles)
// blocks [2560,3840): wo transpose, 64x64 tiles (32 k-tiles x 40 n-tiles)
// blocks [3840,6400): x f32->bf16, 2 float4 per thread
// blocks [6400,8448): cache copy, 16 rows/block, 4 rows per wave (ILP=8)
__global__ __launch_bounds__(256) void prep_kernel(
    const float* __restrict__ kc, const float* __restrict__ vc,
    float* __restrict__ kout, float* __restrict__ vout,
    const int* __restrict__ p_ci, const float* __restrict__ x,
    bf16* __restrict__ xb, const float* __restrict__ wq,
    const float* __restrict__ wk, const float* __restrict__ wv,
    bf16* __restrict__ wqkv_t, const float* __restrict__ wo,
    bf16* __restrict__ wo_t) {
  const int blk = blockIdx.x;
  const int tid = threadIdx.x;
  if (blk >= 3840) {
    if (blk < 6400) {  // ---- x f32 -> bf16, 2 float4 per thread ----
      const long i = (long)(blk - 3840) * 512 + tid;
      const float4 v0 = ((const float4*)x)[i];
      const float4 v1 = ((const float4*)x)[i + 256];
      bf16x4 o0, o1;
      o0.x = (bf16)v0.x; o0.y = (bf16)v0.y; o0.z = (bf16)v0.z; o0.w = (bf16)v0.w;
      o1.x = (bf16)v1.x; o1.y = (bf16)v1.y; o1.z = (bf16)v1.z; o1.w = (bf16)v1.w;
      ((bf16x4*)xb)[i] = o0;
      ((bf16x4*)xb)[i + 256] = o1;
      return;
    }
    // ---- cache copy: block = (bk, 16 rows); wave = 4 contiguous rows ----
    const int cb = blk - 6400;       // 0..2047
    const int bk = cb >> 8;          // 0..7
    const int s0 = (cb & 255) * 16 + (tid >> 6) * 4;
    const int l = tid & 63;
    const int ci = *p_ci;
#pragma unroll
    for (int i = 0; i < 4; ++i) {
      const int s = s0 + i;
      if ((unsigned)(s - ci) < 1024u) continue;  // wave-uniform skip
      const long base = ((long)bk * 4096 + s) * 64 + l;
      ((float4*)kout)[base] = ((const float4*)kc)[base];
      ((float4*)vout)[base] = ((const float4*)vc)[base];
    }
    return;
  }
  // ---- 64x64 transpose-convert, float4 loads, bf16x8 stores ----
  __shared__ float tile[64][65];  // stride 65: 2-way bank alias (free)
  const float* src;
  int k0, n0, col, srcN, dstK;
  bf16* dst;
  if (blk < 2560) {
    const int idx = blk;                   // 40 x 64
    k0 = (idx % 40) * 64; n0 = (idx / 40) * 64;
    dstK = 2560; dst = wqkv_t;
    if (n0 < 2048)      { src = wq; col = n0;        srcN = 2048; }
    else if (n0 < 3072) { src = wk; col = n0 - 2048; srcN = 1024; }
    else                { src = wv; col = n0 - 3072; srcN = 1024; }
  } else {
    const int idx = blk - 2560;            // 32 x 40
    k0 = (idx & 31) * 64; n0 = (idx >> 5) * 64;
    dstK = 2048; dst = wo_t; src = wo; col = n0; srcN = 2560;
  }
  {
    const int rf = tid >> 4, c4 = (tid & 15) * 4;
#pragma unroll
    for (int i = 0; i < 4; ++i) {  // 16 rows per iter, 256B contiguous per row
      const int r = i * 16 + rf;
      const float4 v = *(const float4*)(src + (long)(k0 + r) * srcN + col + c4);
      tile[r][c4] = v.x; tile[r][c4 + 1] = v.y;
      tile[r][c4 + 2] = v.z; tile[r][c4 + 3] = v.w;
    }
  }
  __syncthreads();
  {
    const int nf = tid >> 3, kcq = (tid & 7) * 8;
#pragma unroll
    for (int i = 0; i < 2; ++i) {  // 32 dst rows per iter, 128B/row
      const int nn = i * 32 + nf;
      bf16x8 o8;
#pragma unroll
      for (int j = 0; j < 8; ++j) o8[j] = (bf16)tile[kcq + j][nn];
      *(bf16x8*)(dst + (long)(n0 + nn) * dstK + k0 + kcq) = o8;
    }
  }
}

// ---------------- V path: qkv slice -> vout (f32 scatter) + vt bf16 [d][s] ----
__global__ __launch_bounds__(256) void v_trans_kernel(const bf16* __restrict__ qkv,
                                                      const int* __restrict__ p_ci,
                                                      float* __restrict__ vout,
                                                      bf16* __restrict__ vt) {
  __shared__ float tile[32][33];
  const int s0 = blockIdx.x * 32, d0 = blockIdx.y * 32, bk = blockIdx.z;
  const int b = bk >> 2, kvh = bk & 3;
  const int ci = *p_ci;
  const int tx = threadIdx.x, ty = threadIdx.y;
#pragma unroll
  for (int i = 0; i < 4; ++i) {
    const int s = s0 + ty + i * 8;
    const float val =
        (float)qkv[(long)(b * 1024 + s) * 4096 + (12 + kvh) * 256 + d0 + tx];
    tile[ty + i * 8][tx] = val;
    vout[((long)bk * 4096 + ci + s) * 256 + d0 + tx] = val;
  }
  __syncthreads();
  bf16* dstb = vt + ((long)bk * 256 + d0) * 1024 + s0;
#pragma unroll
  for (int i = 0; i < 4; ++i)
    dstb[(long)(ty + i * 8) * 1024 + tx] = (bf16)tile[tx][ty + i * 8];
}

// ---------------- bf16 MFMA GEMM: C(MxN) = A(MxK) * BT(NxK)^T ----------------
// BK=32, explicit LDS double-buffer; GLL prefetch of tile k+1 issued right
// after the barrier, drains during compute of tile k (one barrier per iter).
template <int BM, int BN, int K, int N, typename OutT>
__global__ __launch_bounds__(256) void gemm_kernel(const bf16* __restrict__ A,
                                                   const bf16* __restrict__ BT,
                                                   OutT* __restrict__ C) {
  __shared__ bf16 As[2 * BM * 32];
  __shared__ bf16 Bs[2 * BN * 32];
  const int bm = blockIdx.x, bn = blockIdx.y;
  const int tid = threadIdx.x;
  const int wave = tid >> 6, lane = tid & 63;
  const int quad = lane >> 4, l16 = lane & 15;
  constexpr int WM = BM / 2, WN = BN / 2;
  constexpr int MI = WM / 16, NI = WN / 16;
  const int wm = (wave & 1) * WM, wn = (wave >> 1) * WN;
  f32x4 acc[MI][NI] = {};
  const int srow = tid >> 2;
  const int sslot = tid & 3;
  const bf16* Ag = A + (long)(bm * BM) * K;
  const bf16* Bg = BT + (long)(bn * BN) * K;
  auto stage = [&](int buf, int k0) {
#pragma unroll
    for (int i = 0; i < BM / 64; ++i) {
      const int r = i * 64 + srow;
      const int cc = (sslot - (r >> 1)) & 3;
      GLL(As + buf * BM * 32 + (i * 256 + wave * 64) * 8,
          Ag + (long)r * K + k0 + cc * 8);
    }
#pragma unroll
    for (int i = 0; i < BN / 64; ++i) {
      const int r = i * 64 + srow;
      const int cc = (sslot - (r >> 1)) & 3;
      GLL(Bs + buf * BN * 32 + (i * 256 + wave * 64) * 8,
          Bg + (long)r * K + k0 + cc * 8);
    }
  };
  stage(0, 0);
  int buf = 0;
  for (int k0 = 0; k0 < K; k0 += 32) {
    __syncthreads();  // drains vmcnt: buf ready; prev iter's ds_reads done
    if (k0 + 32 < K) stage(buf ^ 1, k0 + 32);  // overlaps compute below
    const bf16* Ab = As + buf * BM * 32;
    const bf16* Bb = Bs + buf * BN * 32;
    bf16x8 af[MI], bfr[NI];
#pragma unroll
    for (int mi = 0; mi < MI; ++mi) {
      const int r = wm + mi * 16 + l16;
      af[mi] = *(const bf16x8*)(Ab + r * 32 + (((quad + (r >> 1)) & 3) * 8));
    }
#pragma unroll
    for (int ni = 0; ni < NI; ++ni) {
      const int r = wn + ni * 16 + l16;
      bfr[ni] = *(const bf16x8*)(Bb + r * 32 + (((quad + (r >> 1)) & 3) * 8));
    }
#pragma unroll
    for (int mi = 0; mi < MI; ++mi)
#pragma unroll
      for (int ni = 0; ni < NI; ++ni)
        acc[mi][ni] = MFMA16(af[mi], bfr[ni], acc[mi][ni]);
    buf ^= 1;
  }
  const int crow = bm * BM + wm + quad * 4;
  const int ccol = bn * BN + wn + l16;
#pragma unroll
  for (int mi = 0; mi < MI; ++mi)
#pragma unroll
    for (int ni = 0; ni < NI; ++ni)
#pragma unroll
      for (int r = 0; r < 4; ++r)
        C[(long)(crow + mi * 16 + r) * N + ccol + ni * 16] = (OutT)acc[mi][ni][r];
}

// ---------------- RMSNorm + RoPE (q,k only; fast HW sin/cos) ----------------
// One block per (b,t): 384 threads = 6 waves, wave handles 2 slots (rows).
// bf16x8 vector loads; 32-lane shfl reduction; RoPE partner (d +- 128) via
// __shfl_xor(.,16). No LDS, no barriers.
__global__ __launch_bounds__(384) void normrope_kernel(
    const bf16* __restrict__ qkv, const float* __restrict__ qw,
    const float* __restrict__ kw, const int* __restrict__ p_pos,
    const int* __restrict__ p_ci, float* __restrict__ kout,
    bf16* __restrict__ q_bf, bf16* __restrict__ k_bf) {
  const int bt = blockIdx.x;           // 0..2047
  const int t = bt & 1023, b = bt >> 10;
  const int wave = threadIdx.x >> 6;   // 0..5
  const int lane = threadIdx.x & 63;
  const int half = lane >> 5;          // wave's 2 rows
  const int l32 = lane & 31;
  const int slot = wave * 2 + half;    // 0..11 (0..7 q, 8..11 k) wave-uniform q/k
  const int d0 = l32 * 8;
  const bf16x8 v8 = *(const bf16x8*)(qkv + (long)bt * 4096 + slot * 256 + d0);
  float v[8], ss = 0.0f;
#pragma unroll
  for (int j = 0; j < 8; ++j) {
    v[j] = (float)v8[j];
    ss += v[j] * v[j];
  }
#pragma unroll
  for (int i = 1; i < 32; i <<= 1) ss += __shfl_xor(ss, i);  // 32-lane row sum
  const float rstd = rsqrtf(ss * (1.0f / 256.0f) + 1e-6f);
  const bool isq = slot < 8;
  const float* wp = isq ? qw : kw;
  const float4 w0 = *(const float4*)(wp + d0);
  const float4 w1 = *(const float4*)(wp + d0 + 4);
  float nv[8];
  nv[0] = v[0] * rstd * (1.0f + w0.x); nv[1] = v[1] * rstd * (1.0f + w0.y);
  nv[2] = v[2] * rstd * (1.0f + w0.z); nv[3] = v[3] * rstd * (1.0f + w0.w);
  nv[4] = v[4] * rstd * (1.0f + w1.x); nv[5] = v[5] * rstd * (1.0f + w1.y);
  nv[6] = v[6] * rstd * (1.0f + w1.z); nv[7] = v[7] * rstd * (1.0f + w1.w);
  float pv[8];
#pragma unroll
  for (int j = 0; j < 8; ++j) pv[j] = __shfl_xor(nv[j], 16);  // partner d +- 128
  const float pt = (float)(*p_pos + t);
  const int e0 = (l32 & 15) * 8;  // d0 mod 128
  float outv[8];
#pragma unroll
  for (int j = 0; j < 8; ++j) {
    const float inv_freq = exp2f((float)(e0 + j) * -0.10381025296522976f);
    // v_sin/v_cos take REVOLUTIONS; fract reduction. err ~2e-4 << bf16 eps.
    float rev = pt * inv_freq * 0.15915494309189535f;
    rev = rev - floorf(rev);
    const float sn = __builtin_amdgcn_sinf(rev);
    const float cs = __builtin_amdgcn_cosf(rev);
    outv[j] = (d0 < 128) ? nv[j] * cs - pv[j] * sn : nv[j] * cs + pv[j] * sn;
  }
  bf16x8 ob;
#pragma unroll
  for (int j = 0; j < 8; ++j) ob[j] = (bf16)outv[j];
  if (isq) {
    *(bf16x8*)(q_bf + ((long)(b * 8 + slot) * 1024 + t) * 256 + d0) = ob;
  } else {
    const int kh = slot - 8;
    const int ci = *p_ci;
    *(bf16x8*)(k_bf + ((long)(b * 4 + kh) * 1024 + t) * 256 + d0) = ob;
    float4 f0, f1;
    f0.x = outv[0]; f0.y = outv[1]; f0.z = outv[2]; f0.w = outv[3];
    f1.x = outv[4]; f1.y = outv[5]; f1.z = outv[6]; f1.w = outv[7];
    float* kg = kout + ((long)(b * 4 + kh) * 4096 + ci + t) * 256 + d0;
    *(float4*)(kg) = f0;
    *(float4*)(kg + 4) = f1;
  }
}

// ---------------- flash attention over the T new tokens (all valid, no mask) ----
__global__ __launch_bounds__(256) void attn_kernel(const bf16* __restrict__ q_bf,
                                                   const bf16* __restrict__ k_bf,
                                                   const bf16* __restrict__ vt_bf,
                                                   bf16* __restrict__ attn) {
  __shared__ bf16 Ks[64 * 256];   // [s][d], chunk-swizzled
  __shared__ bf16 Vs[256 * 64];   // [d][s], chunk-swizzled
  __shared__ bf16 Ps[64 * 72];    // [t][s], +8 pad (VALU-written)
  const int qt = blockIdx.x, h = blockIdx.y, b = blockIdx.z;
  const int kvh = h >> 1;
  const int tid = threadIdx.x;
  const int wave = tid >> 6, lane = tid & 63, quad = lane >> 4, l16 = lane & 15;
  bf16x8 qf[8];
  const bf16* qg =
      q_bf + ((long)(b * 8 + h) * 1024 + qt * 64 + wave * 16 + l16) * 256 + quad * 8;
#pragma unroll
  for (int i = 0; i < 8; ++i) qf[i] = *(const bf16x8*)(qg + i * 32);
  f32x4 o[16] = {};
  float m_r[4] = {-1e30f, -1e30f, -1e30f, -1e30f};
  float l_r[4] = {0.f, 0.f, 0.f, 0.f};
  const float sfac = 0.0625f * 1.44269504088896f;  // SCALE * log2(e)
  const bf16* kgb = k_bf + (long)(b * 4 + kvh) * 1024 * 256;
  const bf16* vgb = vt_bf + (long)(b * 4 + kvh) * 256 * 1024;
  const int krow = tid >> 5, kccp = tid & 31;
  const int kcc = kccp ^ (krow & 7);
  const int vrow0 = tid >> 3, vccp = tid & 7;
  for (int st = 0; st < 16; ++st) {
    __syncthreads();  // previous iter's ds_reads done
#pragma unroll
    for (int i = 0; i < 8; ++i) {  // K tile 64x256
      GLL(Ks + (i * 256 + wave * 64) * 8,
          kgb + (long)(st * 64 + krow + i * 8) * 256 + kcc * 8);
    }
#pragma unroll
    for (int i = 0; i < 8; ++i) {  // V^T tile 256x64
      const int vr = vrow0 + i * 32;
      GLL(Vs + (i * 256 + wave * 64) * 8,
          vgb + (long)vr * 1024 + st * 64 + (vccp ^ (vr & 7)) * 8);
    }
    __syncthreads();  // drains vmcnt -> tiles visible
    f32x4 sacc[4] = {};
#pragma unroll
    for (int kk = 0; kk < 8; ++kk) {
#pragma unroll
      for (int ni = 0; ni < 4; ++ni) {
        const int r = ni * 16 + l16;
        bf16x8 kf = *(const bf16x8*)(Ks + r * 256 + (((kk * 4 + quad) ^ (r & 7)) * 8));
        sacc[ni] = MFMA16(qf[kk], kf, sacc[ni]);
      }
    }
    float alpha_r[4];
#pragma unroll
    for (int r = 0; r < 4; ++r) {
      float s0 = sacc[0][r] * sfac, s1 = sacc[1][r] * sfac;
      float s2 = sacc[2][r] * sfac, s3 = sacc[3][r] * sfac;
      float mx = fmaxf(fmaxf(s0, s1), fmaxf(s2, s3));
#pragma unroll
      for (int dd = 1; dd < 16; dd <<= 1) mx = fmaxf(mx, __shfl_xor(mx, dd));
      float mnew = fmaxf(m_r[r], mx);
      float al = exp2f(m_r[r] - mnew);
      m_r[r] = mnew;
      alpha_r[r] = al;
      float p0 = exp2f(s0 - mnew), p1 = exp2f(s1 - mnew);
      float p2 = exp2f(s2 - mnew), p3 = exp2f(s3 - mnew);
      float rs = p0 + p1 + p2 + p3;
#pragma unroll
      for (int dd = 1; dd < 16; dd <<= 1) rs += __shfl_xor(rs, dd);
      l_r[r] = l_r[r] * al + rs;
      const int prow = (wave * 16 + quad * 4 + r) * 72;
      Ps[prow + l16] = (bf16)p0;
      Ps[prow + 16 + l16] = (bf16)p1;
      Ps[prow + 32 + l16] = (bf16)p2;
      Ps[prow + 48 + l16] = (bf16)p3;
    }
#pragma unroll
    for (int n2 = 0; n2 < 16; ++n2) {
      f32x4 tv = o[n2];
      tv.x *= alpha_r[0]; tv.y *= alpha_r[1]; tv.z *= alpha_r[2]; tv.w *= alpha_r[3];
      o[n2] = tv;
    }
    // NOTE: no barrier here. Ps rows [wave*16, wave*16+16) are written and
    // read ONLY by this wave; in-wave ds ordering (compiler lgkmcnt) suffices.
    bf16x8 pf0 = *(const bf16x8*)(Ps + (wave * 16 + l16) * 72 + quad * 8);
    bf16x8 pf1 = *(const bf16x8*)(Ps + (wave * 16 + l16) * 72 + 32 + quad * 8);
#pragma unroll
    for (int n2 = 0; n2 < 16; ++n2) {
      const int r = n2 * 16 + l16;
      bf16x8 vf0 = *(const bf16x8*)(Vs + r * 64 + ((quad ^ (r & 7)) * 8));
      o[n2] = MFMA16(pf0, vf0, o[n2]);
      bf16x8 vf1 = *(const bf16x8*)(Vs + r * 64 + (((4 + quad) ^ (r & 7)) * 8));
      o[n2] = MFMA16(pf1, vf1, o[n2]);
    }
  }
  float inv_l[4];
#pragma unroll
  for (int r = 0; r < 4; ++r) inv_l[r] = 1.0f / l_r[r];
  bf16* og = attn + ((long)(b * 1024 + qt * 64 + wave * 16 + quad * 4)) * 2048 +
             h * 256 + l16;
#pragma unroll
  for (int n2 = 0; n2 < 16; ++n2)
#pragma unroll
    for (int r = 0; r < 4; ++r)
      og[(long)r * 2048 + n2 * 16] = (bf16)(o[n2][r] * inv_l[r]);
}

extern "C" void kernel_launch(void* const* d_in, const int* in_sizes, int n_in,
                              void* d_out, int out_size, void* d_ws, size_t ws_size,
                              hipStream_t stream) {
  const float* x = (const float*)d_in[0];
  const float* k_cache = (const float*)d_in[1];
  const float* v_cache = (const float*)d_in[2];
  const float* wq = (const float*)d_in[3];
  const float* wk = (const float*)d_in[4];
  const float* wv = (const float*)d_in[5];
  const float* wo = (const float*)d_in[6];
  const float* qnw = (const float*)d_in[7];
  const float* knw = (const float*)d_in[8];
  const int* p_pos = (const int*)d_in[9];
  const int* p_ci = (const int*)d_in[10];

  float* out0 = (float*)d_out;                    // (2,1024,2560)
  float* kout = out0 + (long)2 * 1024 * 2560;     // (2,4,4096,256)
  float* vout = kout + (long)2 * 4 * 4096 * 256;  // (2,4,4096,256)

  char* w = (char*)d_ws;
  bf16* x_bf = (bf16*)(w);                  // 2048x2560 bf16        10,485,760 B
  bf16* wqkv_t = (bf16*)(w + 10485760);     // 4096x2560 bf16        20,971,520 B
  bf16* wo_t = (bf16*)(w + 31457280);       // 2560x2048 bf16        10,485,760 B
  bf16* qkv = (bf16*)(w + 41943040);        // 2048x4096 bf16        16,777,216 B
  bf16* q_bf = (bf16*)(w + 58720256);       // (2,8,1024,256) bf16    8,388,608 B
  bf16* k_bf = (bf16*)(w + 67108864);       // (2,4,1024,256) bf16    4,194,304 B
  bf16* vt_bf = (bf16*)(w + 71303168);      // (2,4,256,1024) bf16    4,194,304 B
  bf16* attn_b = (bf16*)(w + 75497472);     // 2048x2048 bf16         8,388,608 B

  // 1. fused prologue (weight transposes first, then x cvt, then cache copy)
  prep_kernel<<<8448, 256, 0, stream>>>(k_cache, v_cache, kout, vout, p_ci, x,
                                        x_bf, wq, wk, wv, wqkv_t, wo, wo_t);

  // 2. fused QKV projection — 128x128 dbuf tiles, bf16 output
  gemm_kernel<128, 128, 2560, 4096, bf16>
      <<<dim3(16, 32), 256, 0, stream>>>(x_bf, wqkv_t, qkv);

  // 3a. V path straight from qkv: vout f32 scatter + vt bf16 transpose
  dim3 tb(32, 8);
  v_trans_kernel<<<dim3(32, 8, 8), tb, 0, stream>>>(qkv, p_ci, vout, vt_bf);

  // 3b. rmsnorm + rope for q,k — vectorized, no LDS/barriers
  normrope_kernel<<<2048, 384, 0, stream>>>(qkv, qnw, knw, p_pos, p_ci,
                                            kout, q_bf, k_bf);

  // 4. attention
  attn_kernel<<<dim3(16, 8, 2), 256, 0, stream>>>(q_bf, k_bf, vt_bf, attn_b);

  // 5. output projection — 64x128 dbuf tiles (grid 32x20 = 640 blocks), f32 out
  gemm_kernel<64, 128, 2048, 2560, float>
      <<<dim3(32, 20), 256, 0, stream>>>(attn_b, wo_t, out0);
}

// Round 2
// 385.504 us; speedup vs baseline: 1.0414x; 1.0414x over previous
//
#include <hip/hip_runtime.h>

typedef __bf16 bf16;
typedef __bf16 bf16x8 __attribute__((ext_vector_type(8)));
typedef __bf16 bf16x4 __attribute__((ext_vector_type(4)));
typedef float f32x4 __attribute__((ext_vector_type(4)));

#define MFMA16(a, b, c) __builtin_amdgcn_mfma_f32_16x16x32_bf16(a, b, c, 0, 0, 0)

// async global -> LDS, 16 B per lane. lds ptr must be WAVE-UNIFORM base;
// HW places lane i at base + i*16.
#define GLL(lds, g)                                                    \
  __builtin_amdgcn_global_load_lds(                                    \
      (const __attribute__((address_space(1))) void*)(g),              \
      (__attribute__((address_space(3))) void*)(lds), 16, 0, 0)

// ---------------- fused prologue ----------------
// Phase order = dispatch order; transposes (longest per-block latency) first
// so the streaming copy fills the tail instead of LDS-round-trip blocks.
// blocks [0,2560):    wqkv transpose, 64x64 tiles (40 k-tiles x 64 n-tiles)
// blocks [2560,3840): wo transpose, 64x64 tiles (32 k-tiles x 40 n-tiles)
// blocks [3840,6400): x f32->bf16, 2 float4 per thread
// blocks [6400,8448): cache copy, 16 rows/block, 4 rows per wave (ILP=8)
__global__ __launch_bounds__(256) void prep_kernel(
    const float* __restrict__ kc, const float* __restrict__ vc,
    float* __restrict__ kout, float* __restrict__ vout,
    const int* __restrict__ p_ci, const float* __restrict__ x,
    bf16* __restrict__ xb, const float* __restrict__ wq,
    const float* __restrict__ wk, const float* __restrict__ wv,
    bf16* __restrict__ wqkv_t, const float* __restrict__ wo,
    bf16* __restrict__ wo_t) {
  const int blk = blockIdx.x;
  const int tid = threadIdx.x;
  if (blk >= 3840) {
    if (blk < 6400) {  // ---- x f32 -> bf16, 2 float4 per thread ----
      const long i = (long)(blk - 3840) * 512 + tid;
      const float4 v0 = ((const float4*)x)[i];
      const float4 v1 = ((const float4*)x)[i + 256];
      bf16x4 o0, o1;
      o0.x = (bf16)v0.x; o0.y = (bf16)v0.y; o0.z = (bf16)v0.z; o0.w = (bf16)v0.w;
      o1.x = (bf16)v1.x; o1.y = (bf16)v1.y; o1.z = (bf16)v1.z; o1.w = (bf16)v1.w;
      ((bf16x4*)xb)[i] = o0;
      ((bf16x4*)xb)[i + 256] = o1;
      return;
    }
    // ---- cache copy: block = (bk, 16 rows); wave = 4 contiguous rows ----
    const int cb = blk - 6400;       // 0..2047
    const int bk = cb >> 8;          // 0..7
    const int s0 = (cb & 255) * 16 + (tid >> 6) * 4;
    const int l = tid & 63;
    const int ci = *p_ci;
#pragma unroll
    for (int i = 0; i < 4; ++i) {
      const int s = s0 + i;
      if ((unsigned)(s - ci) < 1024u) continue;  // wave-uniform skip
      const long base = ((long)bk * 4096 + s) * 64 + l;
      ((float4*)kout)[base] = ((const float4*)kc)[base];
      ((float4*)vout)[base] = ((const float4*)vc)[base];
    }
    return;
  }
  // ---- 64x64 transpose-convert, float4 loads, bf16x8 stores ----
  __shared__ float tile[64][65];  // stride 65: 2-way bank alias (free)
  const float* src;
  int k0, n0, col, srcN, dstK;
  bf16* dst;
  if (blk < 2560) {
    const int idx = blk;                   // 40 x 64
    k0 = (idx % 40) * 64; n0 = (idx / 40) * 64;
    dstK = 2560; dst = wqkv_t;
    if (n0 < 2048)      { src = wq; col = n0;        srcN = 2048; }
    else if (n0 < 3072) { src = wk; col = n0 - 2048; srcN = 1024; }
    else                { src = wv; col = n0 - 3072; srcN = 1024; }
  } else {
    const int idx = blk - 2560;            // 32 x 40
    k0 = (idx & 31) * 64; n0 = (idx >> 5) * 64;
    dstK = 2048; dst = wo_t; src = wo; col = n0; srcN = 2560;
  }
  {
    const int rf = tid >> 4, c4 = (tid & 15) * 4;
#pragma unroll
    for (int i = 0; i < 4; ++i) {  // 16 rows per iter, 256B contiguous per row
      const int r = i * 16 + rf;
      const float4 v = *(const float4*)(src + (long)(k0 + r) * srcN + col + c4);
      tile[r][c4] = v.x; tile[r][c4 + 1] = v.y;
      tile[r][c4 + 2] = v.z; tile[r][c4 + 3] = v.w;
    }
  }
  __syncthreads();
  {
    const int nf = tid >> 3, kcq = (tid & 7) * 8;
#pragma unroll
    for (int i = 0; i < 2; ++i) {  // 32 dst rows per iter, 128B/row
      const int nn = i * 32 + nf;
      bf16x8 o8;
#pragma unroll
      for (int j = 0; j < 8; ++j) o8[j] = (bf16)tile[kcq + j][nn];
      *(bf16x8*)(dst + (long)(n0 + nn) * dstK + k0 + kcq) = o8;
    }
  }
}

// ---------------- V path: qkv slice -> vout (f32 scatter) + vt bf16 [d][s] ----
__global__ __launch_bounds__(256) void v_trans_kernel(const bf16* __restrict__ qkv,
                                                      const int* __restrict__ p_ci,
                                                      float* __restrict__ vout,
                                                      bf16* __restrict__ vt) {
  __shared__ float tile[32][33];
  const int s0 = blockIdx.x * 32, d0 = blockIdx.y * 32, bk = blockIdx.z;
  const int b = bk >> 2, kvh = bk & 3;
  const int ci = *p_ci;
  const int tx = threadIdx.x, ty = threadIdx.y;
#pragma unroll
  for (int i = 0; i < 4; ++i) {
    const int s = s0 + ty + i * 8;
    const float val =
        (float)qkv[(long)(b * 1024 + s) * 4096 + (12 + kvh) * 256 + d0 + tx];
    tile[ty + i * 8][tx] = val;
    vout[((long)bk * 4096 + ci + s) * 256 + d0 + tx] = val;
  }
  __syncthreads();
  bf16* dstb = vt + ((long)bk * 256 + d0) * 1024 + s0;
#pragma unroll
  for (int i = 0; i < 4; ++i)
    dstb[(long)(ty + i * 8) * 1024 + tx] = (bf16)tile[tx][ty + i * 8];
}

// ---------------- bf16 MFMA GEMM: C(MxN) = A(MxK) * BT(NxK)^T ----------------
// BK=32, explicit LDS double-buffer; GLL prefetch of tile k+1 issued right
// after the barrier, drains during compute of tile k (one barrier per iter).
template <int BM, int BN, int K, int N, typename OutT>
__global__ __launch_bounds__(256) void gemm_kernel(const bf16* __restrict__ A,
                                                   const bf16* __restrict__ BT,
                                                   OutT* __restrict__ C) {
  __shared__ bf16 As[2 * BM * 32];
  __shared__ bf16 Bs[2 * BN * 32];
  const int bm = blockIdx.x, bn = blockIdx.y;
  const int tid = threadIdx.x;
  const int wave = tid >> 6, lane = tid & 63;
  const int quad = lane >> 4, l16 = lane & 15;
  constexpr int WM = BM / 2, WN = BN / 2;
  constexpr int MI = WM / 16, NI = WN / 16;
  const int wm = (wave & 1) * WM, wn = (wave >> 1) * WN;
  f32x4 acc[MI][NI] = {};
  const int srow = tid >> 2;
  const int sslot = tid & 3;
  const bf16* Ag = A + (long)(bm * BM) * K;
  const bf16* Bg = BT + (long)(bn * BN) * K;
  auto stage = [&](int buf, int k0) {
#pragma unroll
    for (int i = 0; i < BM / 64; ++i) {
      const int r = i * 64 + srow;
      const int cc = (sslot - (r >> 1)) & 3;
      GLL(As + buf * BM * 32 + (i * 256 + wave * 64) * 8,
          Ag + (long)r * K + k0 + cc * 8);
    }
#pragma unroll
    for (int i = 0; i < BN / 64; ++i) {
      const int r = i * 64 + srow;
      const int cc = (sslot - (r >> 1)) & 3;
      GLL(Bs + buf * BN * 32 + (i * 256 + wave * 64) * 8,
          Bg + (long)r * K + k0 + cc * 8);
    }
  };
  stage(0, 0);
  int buf = 0;
  for (int k0 = 0; k0 < K; k0 += 32) {
    __syncthreads();  // drains vmcnt: buf ready; prev iter's ds_reads done
    if (k0 + 32 < K) stage(buf ^ 1, k0 + 32);  // overlaps compute below
    const bf16* Ab = As + buf * BM * 32;
    const bf16* Bb = Bs + buf * BN * 32;
    bf16x8 af[MI], bfr[NI];
#pragma unroll
    for (int mi = 0; mi < MI; ++mi) {
      const int r = wm + mi * 16 + l16;
      af[mi] = *(const bf16x8*)(Ab + r * 32 + (((quad + (r >> 1)) & 3) * 8));
    }
#pragma unroll
    for (int ni = 0; ni < NI; ++ni) {
      const int r = wn + ni * 16 + l16;
      bfr[ni] = *(const bf16x8*)(Bb + r * 32 + (((quad + (r >> 1)) & 3) * 8));
    }
#pragma unroll
    for (int mi = 0; mi < MI; ++mi)
#pragma unroll
      for (int ni = 0; ni < NI; ++ni)
        acc[mi][ni] = MFMA16(af[mi], bfr[ni], acc[mi][ni]);
    buf ^= 1;
  }
  const int crow = bm * BM + wm + quad * 4;
  const int ccol = bn * BN + wn + l16;
#pragma unroll
  for (int mi = 0; mi < MI; ++mi)
#pragma unroll
    for (int ni = 0; ni < NI; ++ni)
#pragma unroll
      for (int r = 0; r < 4; ++r)
        C[(long)(crow + mi * 16 + r) * N + ccol + ni * 16] = (OutT)acc[mi][ni][r];
}

// ---------------- RMSNorm + RoPE (q,k only; fast HW sin/cos) ----------------
// One block per (b,t): 384 threads = 6 waves, wave handles 2 slots (rows).
// bf16x8 vector loads; 32-lane shfl reduction; RoPE partner (d +- 128) via
// __shfl_xor(.,16). No LDS, no barriers.
__global__ __launch_bounds__(384) void normrope_kernel(
    const bf16* __restrict__ qkv, const float* __restrict__ qw,
    const float* __restrict__ kw, const int* __restrict__ p_pos,
    const int* __restrict__ p_ci, float* __restrict__ kout,
    bf16* __restrict__ q_bf, bf16* __restrict__ k_bf) {
  const int bt = blockIdx.x;           // 0..2047
  const int t = bt & 1023, b = bt >> 10;
  const int wave = threadIdx.x >> 6;   // 0..5
  const int lane = threadIdx.x & 63;
  const int half = lane >> 5;          // wave's 2 rows
  const int l32 = lane & 31;
  const int slot = wave * 2 + half;    // 0..11 (0..7 q, 8..11 k) wave-uniform q/k
  const int d0 = l32 * 8;
  const bf16x8 v8 = *(const bf16x8*)(qkv + (long)bt * 4096 + slot * 256 + d0);
  float v[8], ss = 0.0f;
#pragma unroll
  for (int j = 0; j < 8; ++j) {
    v[j] = (float)v8[j];
    ss += v[j] * v[j];
  }
#pragma unroll
  for (int i = 1; i < 32; i <<= 1) ss += __shfl_xor(ss, i);  // 32-lane row sum
  const float rstd = rsqrtf(ss * (1.0f / 256.0f) + 1e-6f);
  const bool isq = slot < 8;
  const float* wp = isq ? qw : kw;
  const float4 w0 = *(const float4*)(wp + d0);
  const float4 w1 = *(const float4*)(wp + d0 + 4);
  float nv[8];
  nv[0] = v[0] * rstd * (1.0f + w0.x); nv[1] = v[1] * rstd * (1.0f + w0.y);
  nv[2] = v[2] * rstd * (1.0f + w0.z); nv[3] = v[3] * rstd * (1.0f + w0.w);
  nv[4] = v[4] * rstd * (1.0f + w1.x); nv[5] = v[5] * rstd * (1.0f + w1.y);
  nv[6] = v[6] * rstd * (1.0f + w1.z); nv[7] = v[7] * rstd * (1.0f + w1.w);
  float pv[8];
#pragma unroll
  for (int j = 0; j < 8; ++j) pv[j] = __shfl_xor(nv[j], 16);  // partner d +- 128
  const float pt = (float)(*p_pos + t);
  const int e0 = (l32 & 15) * 8;  // d0 mod 128
  float outv[8];
#pragma unroll
  for (int j = 0; j < 8; ++j) {
    const float inv_freq = exp2f((float)(e0 + j) * -0.10381025296522976f);
    // v_sin/v_cos take REVOLUTIONS; fract reduction. err ~2e-4 << bf16 eps.
    float rev = pt * inv_freq * 0.15915494309189535f;
    rev = rev - floorf(rev);
    const float sn = __builtin_amdgcn_sinf(rev);
    const float cs = __builtin_amdgcn_cosf(rev);
    outv[j] = (d0 < 128) ? nv[j] * cs - pv[j] * sn : nv[j] * cs + pv[j] * sn;
  }
  bf16x8 ob;
#pragma unroll
  for (int j = 0; j < 8; ++j) ob[j] = (bf16)outv[j];
  if (isq) {
    *(bf16x8*)(q_bf + ((long)(b * 8 + slot) * 1024 + t) * 256 + d0) = ob;
  } else {
    const int kh = slot - 8;
    const int ci = *p_ci;
    *(bf16x8*)(k_bf + ((long)(b * 4 + kh) * 1024 + t) * 256 + d0) = ob;
    float4 f0, f1;
    f0.x = outv[0]; f0.y = outv[1]; f0.z = outv[2]; f0.w = outv[3];
    f1.x = outv[4]; f1.y = outv[5]; f1.z = outv[6]; f1.w = outv[7];
    float* kg = kout + ((long)(b * 4 + kh) * 4096 + ci + t) * 256 + d0;
    *(float4*)(kg) = f0;
    *(float4*)(kg + 4) = f1;
  }
}

// ---------------- flash attention over the T new tokens (all valid, no mask) ----
// Double-buffered K/V tiles with COUNTED vmcnt: prefetch of step st+1 is
// issued first, then s_waitcnt vmcnt(16) waits only for step st's 16 loads
// (prefetch stays in flight across the raw s_barrier). 1 block/CU, so all
// latency hiding must come from this in-wave ILP.
__global__ __launch_bounds__(256) void attn_kernel(const bf16* __restrict__ q_bf,
                                                   const bf16* __restrict__ k_bf,
                                                   const bf16* __restrict__ vt_bf,
                                                   bf16* __restrict__ attn) {
  __shared__ bf16 Ks[2][64 * 256];   // [s][d], chunk-swizzled
  __shared__ bf16 Vs[2][256 * 64];   // [d][s], chunk-swizzled
  __shared__ bf16 Ps[64 * 72];       // [t][s], +8 pad (VALU-written)
  const int qt = blockIdx.x, h = blockIdx.y, b = blockIdx.z;
  const int kvh = h >> 1;
  const int tid = threadIdx.x;
  const int wave = tid >> 6, lane = tid & 63, quad = lane >> 4, l16 = lane & 15;
  bf16x8 qf[8];
  const bf16* qg =
      q_bf + ((long)(b * 8 + h) * 1024 + qt * 64 + wave * 16 + l16) * 256 + quad * 8;
#pragma unroll
  for (int i = 0; i < 8; ++i) qf[i] = *(const bf16x8*)(qg + i * 32);
  f32x4 o[16] = {};
  float m_r[4] = {-1e30f, -1e30f, -1e30f, -1e30f};
  float l_r[4] = {0.f, 0.f, 0.f, 0.f};
  const float sfac = 0.0625f * 1.44269504088896f;  // SCALE * log2(e)
  const bf16* kgb = k_bf + (long)(b * 4 + kvh) * 1024 * 256;
  const bf16* vgb = vt_bf + (long)(b * 4 + kvh) * 256 * 1024;
  const int krow = tid >> 5, kccp = tid & 31;
  const int kcc = kccp ^ (krow & 7);
  const int vrow0 = tid >> 3, vccp = tid & 7;
  // per-wave: 8 K GLLs + 8 V GLLs = 16 VMEM ops per stage
  auto stage = [&](int sb, int st) {
#pragma unroll
    for (int i = 0; i < 8; ++i) {  // K tile 64x256
      GLL(&Ks[sb][(i * 256 + wave * 64) * 8],
          kgb + (long)(st * 64 + krow + i * 8) * 256 + kcc * 8);
    }
#pragma unroll
    for (int i = 0; i < 8; ++i) {  // V^T tile 256x64
      const int vr = vrow0 + i * 32;
      GLL(&Vs[sb][(i * 256 + wave * 64) * 8],
          vgb + (long)vr * 1024 + st * 64 + (vccp ^ (vr & 7)) * 8);
    }
  };
  stage(0, 0);
  int sb = 0;
  for (int st = 0; st < 16; ++st) {
    if (st < 15) {
      stage(sb ^ 1, st + 1);  // prefetch next tile into other buffer
      // wait only for CURRENT tile's 16 loads; prefetch (16) stays in flight
      asm volatile("s_waitcnt vmcnt(16)" ::: "memory");
    } else {
      asm volatile("s_waitcnt vmcnt(0)" ::: "memory");
    }
    __builtin_amdgcn_s_barrier();  // all waves' current-tile loads landed
    const bf16* Kb = Ks[sb];
    const bf16* Vb = Vs[sb];
    f32x4 sacc[4] = {};
#pragma unroll
    for (int kk = 0; kk < 8; ++kk) {
#pragma unroll
      for (int ni = 0; ni < 4; ++ni) {
        const int r = ni * 16 + l16;
        bf16x8 kf = *(const bf16x8*)(Kb + r * 256 + (((kk * 4 + quad) ^ (r & 7)) * 8));
        sacc[ni] = MFMA16(qf[kk], kf, sacc[ni]);
      }
    }
    float alpha_r[4];
#pragma unroll
    for (int r = 0; r < 4; ++r) {
      float s0 = sacc[0][r] * sfac, s1 = sacc[1][r] * sfac;
      float s2 = sacc[2][r] * sfac, s3 = sacc[3][r] * sfac;
      float mx = fmaxf(fmaxf(s0, s1), fmaxf(s2, s3));
#pragma unroll
      for (int dd = 1; dd < 16; dd <<= 1) mx = fmaxf(mx, __shfl_xor(mx, dd));
      float mnew = fmaxf(m_r[r], mx);
      float al = exp2f(m_r[r] - mnew);
      m_r[r] = mnew;
      alpha_r[r] = al;
      float p0 = exp2f(s0 - mnew), p1 = exp2f(s1 - mnew);
      float p2 = exp2f(s2 - mnew), p3 = exp2f(s3 - mnew);
      float rs = p0 + p1 + p2 + p3;
#pragma unroll
      for (int dd = 1; dd < 16; dd <<= 1) rs += __shfl_xor(rs, dd);
      l_r[r] = l_r[r] * al + rs;
      const int prow = (wave * 16 + quad * 4 + r) * 72;
      Ps[prow + l16] = (bf16)p0;
      Ps[prow + 16 + l16] = (bf16)p1;
      Ps[prow + 32 + l16] = (bf16)p2;
      Ps[prow + 48 + l16] = (bf16)p3;
    }
#pragma unroll
    for (int n2 = 0; n2 < 16; ++n2) {
      f32x4 tv = o[n2];
      tv.x *= alpha_r[0]; tv.y *= alpha_r[1]; tv.z *= alpha_r[2]; tv.w *= alpha_r[3];
      o[n2] = tv;
    }
    // NOTE: no barrier here. Ps rows [wave*16, wave*16+16) are written and
    // read ONLY by this wave; in-wave ds ordering (compiler lgkmcnt) suffices.
    bf16x8 pf0 = *(const bf16x8*)(Ps + (wave * 16 + l16) * 72 + quad * 8);
    bf16x8 pf1 = *(const bf16x8*)(Ps + (wave * 16 + l16) * 72 + 32 + quad * 8);
#pragma unroll
    for (int n2 = 0; n2 < 16; ++n2) {
      const int r = n2 * 16 + l16;
      bf16x8 vf0 = *(const bf16x8*)(Vb + r * 64 + ((quad ^ (r & 7)) * 8));
      o[n2] = MFMA16(pf0, vf0, o[n2]);
      bf16x8 vf1 = *(const bf16x8*)(Vb + r * 64 + (((4 + quad) ^ (r & 7)) * 8));
      o[n2] = MFMA16(pf1, vf1, o[n2]);
    }
    // all ds_reads of buffer sb were consumed by MFMAs above (lgkmcnt waited),
    // so after this barrier it is safe for next iter to overwrite sb.
    __builtin_amdgcn_s_barrier();
    sb ^= 1;
  }
  float inv_l[4];
#pragma unroll
  for (int r = 0; r < 4; ++r) inv_l[r] = 1.0f / l_r[r];
  bf16* og = attn + ((long)(b * 1024 + qt * 64 + wave * 16 + quad * 4)) * 2048 +
             h * 256 + l16;
#pragma unroll
  for (int n2 = 0; n2 < 16; ++n2)
#pragma unroll
    for (int r = 0; r < 4; ++r)
      og[(long)r * 2048 + n2 * 16] = (bf16)(o[n2][r] * inv_l[r]);
}

extern "C" void kernel_launch(void* const* d_in, const int* in_sizes, int n_in,
                              void* d_out, int out_size, void* d_ws, size_t ws_size,
                              hipStream_t stream) {
  const float* x = (const float*)d_in[0];
  const float* k_cache = (const float*)d_in[1];
  const float* v_cache = (const float*)d_in[2];
  const float* wq = (const float*)d_in[3];
  const float* wk = (const float*)d_in[4];
  const float* wv = (const float*)d_in[5];
  const float* wo = (const float*)d_in[6];
  const float* qnw = (const float*)d_in[7];
  const float* knw = (const float*)d_in[8];
  const int* p_pos = (const int*)d_in[9];
  const int* p_ci = (const int*)d_in[10];

  float* out0 = (float*)d_out;                    // (2,1024,2560)
  float* kout = out0 + (long)2 * 1024 * 2560;     // (2,4,4096,256)
  float* vout = kout + (long)2 * 4 * 4096 * 256;  // (2,4,4096,256)

  char* w = (char*)d_ws;
  bf16* x_bf = (bf16*)(w);                  // 2048x2560 bf16        10,485,760 B
  bf16* wqkv_t = (bf16*)(w + 10485760);     // 4096x2560 bf16        20,971,520 B
  bf16* wo_t = (bf16*)(w + 31457280);       // 2560x2048 bf16        10,485,760 B
  bf16* qkv = (bf16*)(w + 41943040);        // 2048x4096 bf16        16,777,216 B
  bf16* q_bf = (bf16*)(w + 58720256);       // (2,8,1024,256) bf16    8,388,608 B
  bf16* k_bf = (bf16*)(w + 67108864);       // (2,4,1024,256) bf16    4,194,304 B
  bf16* vt_bf = (bf16*)(w + 71303168);      // (2,4,256,1024) bf16    4,194,304 B
  bf16* attn_b = (bf16*)(w + 75497472);     // 2048x2048 bf16         8,388,608 B

  // 1. fused prologue (weight transposes first, then x cvt, then cache copy)
  prep_kernel<<<8448, 256, 0, stream>>>(k_cache, v_cache, kout, vout, p_ci, x,
                                        x_bf, wq, wk, wv, wqkv_t, wo, wo_t);

  // 2. fused QKV projection — 128x128 dbuf tiles, bf16 output
  gemm_kernel<128, 128, 2560, 4096, bf16>
      <<<dim3(16, 32), 256, 0, stream>>>(x_bf, wqkv_t, qkv);

  // 3a. V path straight from qkv: vout f32 scatter + vt bf16 transpose
  dim3 tb(32, 8);
  v_trans_kernel<<<dim3(32, 8, 8), tb, 0, stream>>>(qkv, p_ci, vout, vt_bf);

  // 3b. rmsnorm + rope for q,k — vectorized, no LDS/barriers
  normrope_kernel<<<2048, 384, 0, stream>>>(qkv, qnw, knw, p_pos, p_ci,
                                            kout, q_bf, k_bf);

  // 4. attention (double-buffered, counted vmcnt)
  attn_kernel<<<dim3(16, 8, 2), 256, 0, stream>>>(q_bf, k_bf, vt_bf, attn_b);

  // 5. output projection — 64x128 dbuf tiles (grid 32x20 = 640 blocks), f32 out
  gemm_kernel<64, 128, 2048, 2560, float>
      <<<dim3(32, 20), 256, 0, stream>>>(attn_b, wo_t, out0);
}

// Round 3
// 371.960 us; speedup vs baseline: 1.0793x; 1.0364x over previous
//
#include <hip/hip_runtime.h>

typedef __bf16 bf16;
typedef __bf16 bf16x8 __attribute__((ext_vector_type(8)));
typedef __bf16 bf16x4 __attribute__((ext_vector_type(4)));
typedef float f32x4 __attribute__((ext_vector_type(4)));

#define MFMA16(a, b, c) __builtin_amdgcn_mfma_f32_16x16x32_bf16(a, b, c, 0, 0, 0)

// async global -> LDS, 16 B per lane. lds ptr must be WAVE-UNIFORM base;
// HW places lane i at base + i*16.
#define GLL(lds, g)                                                    \
  __builtin_amdgcn_global_load_lds(                                    \
      (const __attribute__((address_space(1))) void*)(g),              \
      (__attribute__((address_space(3))) void*)(lds), 16, 0, 0)

// ---------------- weight transposes (LDS round-trip phase, isolated) --------
// blocks [0,2560):    wqkv transpose, 64x64 tiles (40 k-tiles x 64 n-tiles)
// blocks [2560,3840): wo transpose, 64x64 tiles (32 k-tiles x 40 n-tiles)
// nt loads: weights are read exactly once; outputs (re-read by GEMMs) use
// regular stores so they allocate in L2/L3.
__global__ __launch_bounds__(256) void trans_kernel(
    const float* __restrict__ wq, const float* __restrict__ wk,
    const float* __restrict__ wv, bf16* __restrict__ wqkv_t,
    const float* __restrict__ wo, bf16* __restrict__ wo_t) {
  const int blk = blockIdx.x;
  const int tid = threadIdx.x;
  __shared__ float tile[64][65];  // stride 65: 2-way bank alias (free)
  const float* src;
  int k0, n0, col, srcN, dstK;
  bf16* dst;
  if (blk < 2560) {
    const int idx = blk;                   // 40 x 64
    k0 = (idx % 40) * 64; n0 = (idx / 40) * 64;
    dstK = 2560; dst = wqkv_t;
    if (n0 < 2048)      { src = wq; col = n0;        srcN = 2048; }
    else if (n0 < 3072) { src = wk; col = n0 - 2048; srcN = 1024; }
    else                { src = wv; col = n0 - 3072; srcN = 1024; }
  } else {
    const int idx = blk - 2560;            // 32 x 40
    k0 = (idx & 31) * 64; n0 = (idx >> 5) * 64;
    dstK = 2048; dst = wo_t; src = wo; col = n0; srcN = 2560;
  }
  {
    const int rf = tid >> 4, c4 = (tid & 15) * 4;
#pragma unroll
    for (int i = 0; i < 4; ++i) {  // 16 rows per iter, 256B contiguous per row
      const int r = i * 16 + rf;
      const f32x4 v = __builtin_nontemporal_load(
          (const f32x4*)(src + (long)(k0 + r) * srcN + col + c4));
      tile[r][c4] = v.x; tile[r][c4 + 1] = v.y;
      tile[r][c4 + 2] = v.z; tile[r][c4 + 3] = v.w;
    }
  }
  __syncthreads();
  {
    const int nf = tid >> 3, kcq = (tid & 7) * 8;
#pragma unroll
    for (int i = 0; i < 2; ++i) {  // 32 dst rows per iter, 128B/row
      const int nn = i * 32 + nf;
      bf16x8 o8;
#pragma unroll
      for (int j = 0; j < 8; ++j) o8[j] = (bf16)tile[kcq + j][nn];
      *(bf16x8*)(dst + (long)(n0 + nn) * dstK + k0 + kcq) = o8;
    }
  }
}

// ---------------- pure streaming phase: cache copy + x cvt ------------------
// blocks [0,2048):    cache copy, 16 rows/block, 4 rows/wave, nt both ways,
//                     v stream staggered by s^2048 to decorrelate channels.
// blocks [2048,4608): x f32->bf16, 2 float4 per thread, nt loads.
__global__ __launch_bounds__(256) void stream_kernel(
    const float* __restrict__ kc, const float* __restrict__ vc,
    float* __restrict__ kout, float* __restrict__ vout,
    const int* __restrict__ p_ci, const float* __restrict__ x,
    bf16* __restrict__ xb) {
  const int blk = blockIdx.x;
  const int tid = threadIdx.x;
  if (blk >= 2048) {  // ---- x f32 -> bf16 ----
    const long i = (long)(blk - 2048) * 512 + tid;
    const f32x4 v0 = __builtin_nontemporal_load((const f32x4*)x + i);
    const f32x4 v1 = __builtin_nontemporal_load((const f32x4*)x + i + 256);
    bf16x4 o0, o1;
    o0.x = (bf16)v0.x; o0.y = (bf16)v0.y; o0.z = (bf16)v0.z; o0.w = (bf16)v0.w;
    o1.x = (bf16)v1.x; o1.y = (bf16)v1.y; o1.z = (bf16)v1.z; o1.w = (bf16)v1.w;
    ((bf16x4*)xb)[i] = o0;
    ((bf16x4*)xb)[i + 256] = o1;
    return;
  }
  // ---- cache copy ----
  const int cb = blk;              // 0..2047
  const int bk = cb >> 8;          // 0..7
  const int s0 = (cb & 255) * 16 + (tid >> 6) * 4;
  const int l = tid & 63;
  const int ci = *p_ci;
  f32x4 kr[4], vr[4];
#pragma unroll
  for (int i = 0; i < 4; ++i) {  // all loads issued first: 8 in flight
    const int sk = s0 + i;
    const int sv = sk ^ 2048;    // bijective stagger: decorrelate k/v streams
    if ((unsigned)(sk - ci) >= 1024u)
      kr[i] = __builtin_nontemporal_load((const f32x4*)kc +
                                         ((long)bk * 4096 + sk) * 64 + l);
    if ((unsigned)(sv - ci) >= 1024u)
      vr[i] = __builtin_nontemporal_load((const f32x4*)vc +
                                         ((long)bk * 4096 + sv) * 64 + l);
  }
#pragma unroll
  for (int i = 0; i < 4; ++i) {
    const int sk = s0 + i;
    const int sv = sk ^ 2048;
    if ((unsigned)(sk - ci) >= 1024u)
      __builtin_nontemporal_store(kr[i], (f32x4*)kout +
                                  ((long)bk * 4096 + sk) * 64 + l);
    if ((unsigned)(sv - ci) >= 1024u)
      __builtin_nontemporal_store(vr[i], (f32x4*)vout +
                                  ((long)bk * 4096 + sv) * 64 + l);
  }
}

// ---------------- V path: qkv slice -> vout (f32 scatter) + vt bf16 [d][s] ----
__global__ __launch_bounds__(256) void v_trans_kernel(const bf16* __restrict__ qkv,
                                                      const int* __restrict__ p_ci,
                                                      float* __restrict__ vout,
                                                      bf16* __restrict__ vt) {
  __shared__ float tile[32][33];
  const int s0 = blockIdx.x * 32, d0 = blockIdx.y * 32, bk = blockIdx.z;
  const int b = bk >> 2, kvh = bk & 3;
  const int ci = *p_ci;
  const int tx = threadIdx.x, ty = threadIdx.y;
#pragma unroll
  for (int i = 0; i < 4; ++i) {
    const int s = s0 + ty + i * 8;
    const float val =
        (float)qkv[(long)(b * 1024 + s) * 4096 + (12 + kvh) * 256 + d0 + tx];
    tile[ty + i * 8][tx] = val;
    vout[((long)bk * 4096 + ci + s) * 256 + d0 + tx] = val;
  }
  __syncthreads();
  bf16* dstb = vt + ((long)bk * 256 + d0) * 1024 + s0;
#pragma unroll
  for (int i = 0; i < 4; ++i)
    dstb[(long)(ty + i * 8) * 1024 + tx] = (bf16)tile[tx][ty + i * 8];
}

// ---------------- bf16 MFMA GEMM: C(MxN) = A(MxK) * BT(NxK)^T ----------------
// BK=32, explicit LDS double-buffer; GLL prefetch of tile k+1 issued right
// after the barrier, drains during compute of tile k (one barrier per iter).
template <int BM, int BN, int K, int N, typename OutT>
__global__ __launch_bounds__(256) void gemm_kernel(const bf16* __restrict__ A,
                                                   const bf16* __restrict__ BT,
                                                   OutT* __restrict__ C) {
  __shared__ bf16 As[2 * BM * 32];
  __shared__ bf16 Bs[2 * BN * 32];
  const int bm = blockIdx.x, bn = blockIdx.y;
  const int tid = threadIdx.x;
  const int wave = tid >> 6, lane = tid & 63;
  const int quad = lane >> 4, l16 = lane & 15;
  constexpr int WM = BM / 2, WN = BN / 2;
  constexpr int MI = WM / 16, NI = WN / 16;
  const int wm = (wave & 1) * WM, wn = (wave >> 1) * WN;
  f32x4 acc[MI][NI] = {};
  const int srow = tid >> 2;
  const int sslot = tid & 3;
  const bf16* Ag = A + (long)(bm * BM) * K;
  const bf16* Bg = BT + (long)(bn * BN) * K;
  auto stage = [&](int buf, int k0) {
#pragma unroll
    for (int i = 0; i < BM / 64; ++i) {
      const int r = i * 64 + srow;
      const int cc = (sslot - (r >> 1)) & 3;
      GLL(As + buf * BM * 32 + (i * 256 + wave * 64) * 8,
          Ag + (long)r * K + k0 + cc * 8);
    }
#pragma unroll
    for (int i = 0; i < BN / 64; ++i) {
      const int r = i * 64 + srow;
      const int cc = (sslot - (r >> 1)) & 3;
      GLL(Bs + buf * BN * 32 + (i * 256 + wave * 64) * 8,
          Bg + (long)r * K + k0 + cc * 8);
    }
  };
  stage(0, 0);
  int buf = 0;
  for (int k0 = 0; k0 < K; k0 += 32) {
    __syncthreads();  // drains vmcnt: buf ready; prev iter's ds_reads done
    if (k0 + 32 < K) stage(buf ^ 1, k0 + 32);  // overlaps compute below
    const bf16* Ab = As + buf * BM * 32;
    const bf16* Bb = Bs + buf * BN * 32;
    bf16x8 af[MI], bfr[NI];
#pragma unroll
    for (int mi = 0; mi < MI; ++mi) {
      const int r = wm + mi * 16 + l16;
      af[mi] = *(const bf16x8*)(Ab + r * 32 + (((quad + (r >> 1)) & 3) * 8));
    }
#pragma unroll
    for (int ni = 0; ni < NI; ++ni) {
      const int r = wn + ni * 16 + l16;
      bfr[ni] = *(const bf16x8*)(Bb + r * 32 + (((quad + (r >> 1)) & 3) * 8));
    }
#pragma unroll
    for (int mi = 0; mi < MI; ++mi)
#pragma unroll
      for (int ni = 0; ni < NI; ++ni)
        acc[mi][ni] = MFMA16(af[mi], bfr[ni], acc[mi][ni]);
    buf ^= 1;
  }
  const int crow = bm * BM + wm + quad * 4;
  const int ccol = bn * BN + wn + l16;
#pragma unroll
  for (int mi = 0; mi < MI; ++mi)
#pragma unroll
    for (int ni = 0; ni < NI; ++ni)
#pragma unroll
      for (int r = 0; r < 4; ++r)
        C[(long)(crow + mi * 16 + r) * N + ccol + ni * 16] = (OutT)acc[mi][ni][r];
}

// ---------------- RMSNorm + RoPE (q,k only; fast HW sin/cos) ----------------
// One block per (b,t): 384 threads = 6 waves, wave handles 2 slots (rows).
// bf16x8 vector loads; 32-lane shfl reduction; RoPE partner (d +- 128) via
// __shfl_xor(.,16). No LDS, no barriers.
__global__ __launch_bounds__(384) void normrope_kernel(
    const bf16* __restrict__ qkv, const float* __restrict__ qw,
    const float* __restrict__ kw, const int* __restrict__ p_pos,
    const int* __restrict__ p_ci, float* __restrict__ kout,
    bf16* __restrict__ q_bf, bf16* __restrict__ k_bf) {
  const int bt = blockIdx.x;           // 0..2047
  const int t = bt & 1023, b = bt >> 10;
  const int wave = threadIdx.x >> 6;   // 0..5
  const int lane = threadIdx.x & 63;
  const int half = lane >> 5;          // wave's 2 rows
  const int l32 = lane & 31;
  const int slot = wave * 2 + half;    // 0..11 (0..7 q, 8..11 k) wave-uniform q/k
  const int d0 = l32 * 8;
  const bf16x8 v8 = *(const bf16x8*)(qkv + (long)bt * 4096 + slot * 256 + d0);
  float v[8], ss = 0.0f;
#pragma unroll
  for (int j = 0; j < 8; ++j) {
    v[j] = (float)v8[j];
    ss += v[j] * v[j];
  }
#pragma unroll
  for (int i = 1; i < 32; i <<= 1) ss += __shfl_xor(ss, i);  // 32-lane row sum
  const float rstd = rsqrtf(ss * (1.0f / 256.0f) + 1e-6f);
  const bool isq = slot < 8;
  const float* wp = isq ? qw : kw;
  const float4 w0 = *(const float4*)(wp + d0);
  const float4 w1 = *(const float4*)(wp + d0 + 4);
  float nv[8];
  nv[0] = v[0] * rstd * (1.0f + w0.x); nv[1] = v[1] * rstd * (1.0f + w0.y);
  nv[2] = v[2] * rstd * (1.0f + w0.z); nv[3] = v[3] * rstd * (1.0f + w0.w);
  nv[4] = v[4] * rstd * (1.0f + w1.x); nv[5] = v[5] * rstd * (1.0f + w1.y);
  nv[6] = v[6] * rstd * (1.0f + w1.z); nv[7] = v[7] * rstd * (1.0f + w1.w);
  float pv[8];
#pragma unroll
  for (int j = 0; j < 8; ++j) pv[j] = __shfl_xor(nv[j], 16);  // partner d +- 128
  const float pt = (float)(*p_pos + t);
  const int e0 = (l32 & 15) * 8;  // d0 mod 128
  float outv[8];
#pragma unroll
  for (int j = 0; j < 8; ++j) {
    const float inv_freq = exp2f((float)(e0 + j) * -0.10381025296522976f);
    // v_sin/v_cos take REVOLUTIONS; fract reduction. err ~2e-4 << bf16 eps.
    float rev = pt * inv_freq * 0.15915494309189535f;
    rev = rev - floorf(rev);
    const float sn = __builtin_amdgcn_sinf(rev);
    const float cs = __builtin_amdgcn_cosf(rev);
    outv[j] = (d0 < 128) ? nv[j] * cs - pv[j] * sn : nv[j] * cs + pv[j] * sn;
  }
  bf16x8 ob;
#pragma unroll
  for (int j = 0; j < 8; ++j) ob[j] = (bf16)outv[j];
  if (isq) {
    *(bf16x8*)(q_bf + ((long)(b * 8 + slot) * 1024 + t) * 256 + d0) = ob;
  } else {
    const int kh = slot - 8;
    const int ci = *p_ci;
    *(bf16x8*)(k_bf + ((long)(b * 4 + kh) * 1024 + t) * 256 + d0) = ob;
    float4 f0, f1;
    f0.x = outv[0]; f0.y = outv[1]; f0.z = outv[2]; f0.w = outv[3];
    f1.x = outv[4]; f1.y = outv[5]; f1.z = outv[6]; f1.w = outv[7];
    float* kg = kout + ((long)(b * 4 + kh) * 4096 + ci + t) * 256 + d0;
    *(float4*)(kg) = f0;
    *(float4*)(kg + 4) = f1;
  }
}

// ---------------- flash attention over the T new tokens (all valid, no mask) ----
// Double-buffered K/V tiles with COUNTED vmcnt: prefetch of step st+1 is
// issued first, then s_waitcnt vmcnt(16) waits only for step st's 16 loads
// (prefetch stays in flight across the raw s_barrier). 1 block/CU, so all
// latency hiding must come from this in-wave ILP.
__global__ __launch_bounds__(256) void attn_kernel(const bf16* __restrict__ q_bf,
                                                   const bf16* __restrict__ k_bf,
                                                   const bf16* __restrict__ vt_bf,
                                                   bf16* __restrict__ attn) {
  __shared__ bf16 Ks[2][64 * 256];   // [s][d], chunk-swizzled
  __shared__ bf16 Vs[2][256 * 64];   // [d][s], chunk-swizzled
  __shared__ bf16 Ps[64 * 72];       // [t][s], +8 pad (VALU-written)
  const int qt = blockIdx.x, h = blockIdx.y, b = blockIdx.z;
  const int kvh = h >> 1;
  const int tid = threadIdx.x;
  const int wave = tid >> 6, lane = tid & 63, quad = lane >> 4, l16 = lane & 15;
  bf16x8 qf[8];
  const bf16* qg =
      q_bf + ((long)(b * 8 + h) * 1024 + qt * 64 + wave * 16 + l16) * 256 + quad * 8;
#pragma unroll
  for (int i = 0; i < 8; ++i) qf[i] = *(const bf16x8*)(qg + i * 32);
  f32x4 o[16] = {};
  float m_r[4] = {-1e30f, -1e30f, -1e30f, -1e30f};
  float l_r[4] = {0.f, 0.f, 0.f, 0.f};
  const float sfac = 0.0625f * 1.44269504088896f;  // SCALE * log2(e)
  const bf16* kgb = k_bf + (long)(b * 4 + kvh) * 1024 * 256;
  const bf16* vgb = vt_bf + (long)(b * 4 + kvh) * 256 * 1024;
  const int krow = tid >> 5, kccp = tid & 31;
  const int kcc = kccp ^ (krow & 7);
  const int vrow0 = tid >> 3, vccp = tid & 7;
  // per-wave: 8 K GLLs + 8 V GLLs = 16 VMEM ops per stage
  auto stage = [&](int sb, int st) {
#pragma unroll
    for (int i = 0; i < 8; ++i) {  // K tile 64x256
      GLL(&Ks[sb][(i * 256 + wave * 64) * 8],
          kgb + (long)(st * 64 + krow + i * 8) * 256 + kcc * 8);
    }
#pragma unroll
    for (int i = 0; i < 8; ++i) {  // V^T tile 256x64
      const int vr = vrow0 + i * 32;
      GLL(&Vs[sb][(i * 256 + wave * 64) * 8],
          vgb + (long)vr * 1024 + st * 64 + (vccp ^ (vr & 7)) * 8);
    }
  };
  stage(0, 0);
  int sb = 0;
  for (int st = 0; st < 16; ++st) {
    if (st < 15) {
      stage(sb ^ 1, st + 1);  // prefetch next tile into other buffer
      // wait only for CURRENT tile's 16 loads; prefetch (16) stays in flight
      asm volatile("s_waitcnt vmcnt(16)" ::: "memory");
    } else {
      asm volatile("s_waitcnt vmcnt(0)" ::: "memory");
    }
    __builtin_amdgcn_s_barrier();  // all waves' current-tile loads landed
    const bf16* Kb = Ks[sb];
    const bf16* Vb = Vs[sb];
    f32x4 sacc[4] = {};
#pragma unroll
    for (int kk = 0; kk < 8; ++kk) {
#pragma unroll
      for (int ni = 0; ni < 4; ++ni) {
        const int r = ni * 16 + l16;
        bf16x8 kf = *(const bf16x8*)(Kb + r * 256 + (((kk * 4 + quad) ^ (r & 7)) * 8));
        sacc[ni] = MFMA16(qf[kk], kf, sacc[ni]);
      }
    }
    float alpha_r[4];
#pragma unroll
    for (int r = 0; r < 4; ++r) {
      float s0 = sacc[0][r] * sfac, s1 = sacc[1][r] * sfac;
      float s2 = sacc[2][r] * sfac, s3 = sacc[3][r] * sfac;
      float mx = fmaxf(fmaxf(s0, s1), fmaxf(s2, s3));
#pragma unroll
      for (int dd = 1; dd < 16; dd <<= 1) mx = fmaxf(mx, __shfl_xor(mx, dd));
      float mnew = fmaxf(m_r[r], mx);
      float al = exp2f(m_r[r] - mnew);
      m_r[r] = mnew;
      alpha_r[r] = al;
      float p0 = exp2f(s0 - mnew), p1 = exp2f(s1 - mnew);
      float p2 = exp2f(s2 - mnew), p3 = exp2f(s3 - mnew);
      float rs = p0 + p1 + p2 + p3;
#pragma unroll
      for (int dd = 1; dd < 16; dd <<= 1) rs += __shfl_xor(rs, dd);
      l_r[r] = l_r[r] * al + rs;
      const int prow = (wave * 16 + quad * 4 + r) * 72;
      Ps[prow + l16] = (bf16)p0;
      Ps[prow + 16 + l16] = (bf16)p1;
      Ps[prow + 32 + l16] = (bf16)p2;
      Ps[prow + 48 + l16] = (bf16)p3;
    }
#pragma unroll
    for (int n2 = 0; n2 < 16; ++n2) {
      f32x4 tv = o[n2];
      tv.x *= alpha_r[0]; tv.y *= alpha_r[1]; tv.z *= alpha_r[2]; tv.w *= alpha_r[3];
      o[n2] = tv;
    }
    // NOTE: no barrier here. Ps rows [wave*16, wave*16+16) are written and
    // read ONLY by this wave; in-wave ds ordering (compiler lgkmcnt) suffices.
    bf16x8 pf0 = *(const bf16x8*)(Ps + (wave * 16 + l16) * 72 + quad * 8);
    bf16x8 pf1 = *(const bf16x8*)(Ps + (wave * 16 + l16) * 72 + 32 + quad * 8);
#pragma unroll
    for (int n2 = 0; n2 < 16; ++n2) {
      const int r = n2 * 16 + l16;
      bf16x8 vf0 = *(const bf16x8*)(Vb + r * 64 + ((quad ^ (r & 7)) * 8));
      o[n2] = MFMA16(pf0, vf0, o[n2]);
      bf16x8 vf1 = *(const bf16x8*)(Vb + r * 64 + (((4 + quad) ^ (r & 7)) * 8));
      o[n2] = MFMA16(pf1, vf1, o[n2]);
    }
    // all ds_reads of buffer sb were consumed by MFMAs above (lgkmcnt waited),
    // so after this barrier it is safe for next iter to overwrite sb.
    __builtin_amdgcn_s_barrier();
    sb ^= 1;
  }
  float inv_l[4];
#pragma unroll
  for (int r = 0; r < 4; ++r) inv_l[r] = 1.0f / l_r[r];
  bf16* og = attn + ((long)(b * 1024 + qt * 64 + wave * 16 + quad * 4)) * 2048 +
             h * 256 + l16;
#pragma unroll
  for (int n2 = 0; n2 < 16; ++n2)
#pragma unroll
    for (int r = 0; r < 4; ++r)
      og[(long)r * 2048 + n2 * 16] = (bf16)(o[n2][r] * inv_l[r]);
}

extern "C" void kernel_launch(void* const* d_in, const int* in_sizes, int n_in,
                              void* d_out, int out_size, void* d_ws, size_t ws_size,
                              hipStream_t stream) {
  const float* x = (const float*)d_in[0];
  const float* k_cache = (const float*)d_in[1];
  const float* v_cache = (const float*)d_in[2];
  const float* wq = (const float*)d_in[3];
  const float* wk = (const float*)d_in[4];
  const float* wv = (const float*)d_in[5];
  const float* wo = (const float*)d_in[6];
  const float* qnw = (const float*)d_in[7];
  const float* knw = (const float*)d_in[8];
  const int* p_pos = (const int*)d_in[9];
  const int* p_ci = (const int*)d_in[10];

  float* out0 = (float*)d_out;                    // (2,1024,2560)
  float* kout = out0 + (long)2 * 1024 * 2560;     // (2,4,4096,256)
  float* vout = kout + (long)2 * 4 * 4096 * 256;  // (2,4,4096,256)

  char* w = (char*)d_ws;
  bf16* x_bf = (bf16*)(w);                  // 2048x2560 bf16        10,485,760 B
  bf16* wqkv_t = (bf16*)(w + 10485760);     // 4096x2560 bf16        20,971,520 B
  bf16* wo_t = (bf16*)(w + 31457280);       // 2560x2048 bf16        10,485,760 B
  bf16* qkv = (bf16*)(w + 41943040);        // 2048x4096 bf16        16,777,216 B
  bf16* q_bf = (bf16*)(w + 58720256);       // (2,8,1024,256) bf16    8,388,608 B
  bf16* k_bf = (bf16*)(w + 67108864);       // (2,4,1024,256) bf16    4,194,304 B
  bf16* vt_bf = (bf16*)(w + 71303168);      // (2,4,256,1024) bf16    4,194,304 B
  bf16* attn_b = (bf16*)(w + 75497472);     // 2048x2048 bf16         8,388,608 B

  // 1a. weight transposes (LDS phase, isolated dispatch for attribution)
  trans_kernel<<<3840, 256, 0, stream>>>(wq, wk, wv, wqkv_t, wo, wo_t);

  // 1b. pure streaming: cache copy (nt, staggered) + x f32->bf16
  stream_kernel<<<4608, 256, 0, stream>>>(k_cache, v_cache, kout, vout, p_ci,
                                          x, x_bf);

  // 2. fused QKV projection — 128x128 dbuf tiles, bf16 output
  gemm_kernel<128, 128, 2560, 4096, bf16>
      <<<dim3(16, 32), 256, 0, stream>>>(x_bf, wqkv_t, qkv);

  // 3a. V path straight from qkv: vout f32 scatter + vt bf16 transpose
  dim3 tb(32, 8);
  v_trans_kernel<<<dim3(32, 8, 8), tb, 0, stream>>>(qkv, p_ci, vout, vt_bf);

  // 3b. rmsnorm + rope for q,k — vectorized, no LDS/barriers
  normrope_kernel<<<2048, 384, 0, stream>>>(qkv, qnw, knw, p_pos, p_ci,
                                            kout, q_bf, k_bf);

  // 4. attention (double-buffered, counted vmcnt)
  attn_kernel<<<dim3(16, 8, 2), 256, 0, stream>>>(q_bf, k_bf, vt_bf, attn_b);

  // 5. output projection — 64x128 dbuf tiles (grid 32x20 = 640 blocks), f32 out
  gemm_kernel<64, 128, 2048, 2560, float>
      <<<dim3(32, 20), 256, 0, stream>>>(attn_b, wo_t, out0);
}

// Round 4
// 364.603 us; speedup vs baseline: 1.1011x; 1.0202x over previous
//
#include <hip/hip_runtime.h>

typedef __bf16 bf16;
typedef __bf16 bf16x8 __attribute__((ext_vector_type(8)));
typedef __bf16 bf16x4 __attribute__((ext_vector_type(4)));
typedef float f32x4 __attribute__((ext_vector_type(4)));

#define MFMA16(a, b, c) __builtin_amdgcn_mfma_f32_16x16x32_bf16(a, b, c, 0, 0, 0)

// async global -> LDS, 16 B per lane. lds ptr must be WAVE-UNIFORM base;
// HW places lane i at base + i*16.
#define GLL(lds, g)                                                    \
  __builtin_amdgcn_global_load_lds(                                    \
      (const __attribute__((address_space(1))) void*)(g),              \
      (__attribute__((address_space(3))) void*)(lds), 16, 0, 0)

template <int N>
__device__ __forceinline__ void waitcnt_vm() {
  if constexpr (N == 0) asm volatile("s_waitcnt vmcnt(0)" ::: "memory");
  else if constexpr (N == 1) asm volatile("s_waitcnt vmcnt(1)" ::: "memory");
  else if constexpr (N == 2) asm volatile("s_waitcnt vmcnt(2)" ::: "memory");
  else if constexpr (N == 3) asm volatile("s_waitcnt vmcnt(3)" ::: "memory");
  else if constexpr (N == 4) asm volatile("s_waitcnt vmcnt(4)" ::: "memory");
  else static_assert(N <= 4, "add case");
}

// ---------------- weight transposes (LDS round-trip phase, isolated) --------
// blocks [0,2560):    wqkv transpose, 64x64 tiles (40 k-tiles x 64 n-tiles)
// blocks [2560,3840): wo transpose, 64x64 tiles (32 k-tiles x 40 n-tiles)
// nt loads: weights are read exactly once; outputs (re-read by GEMMs) use
// regular stores so they allocate in L2/L3.
__global__ __launch_bounds__(256) void trans_kernel(
    const float* __restrict__ wq, const float* __restrict__ wk,
    const float* __restrict__ wv, bf16* __restrict__ wqkv_t,
    const float* __restrict__ wo, bf16* __restrict__ wo_t) {
  const int blk = blockIdx.x;
  const int tid = threadIdx.x;
  __shared__ float tile[64][65];  // stride 65: 2-way bank alias (free)
  const float* src;
  int k0, n0, col, srcN, dstK;
  bf16* dst;
  if (blk < 2560) {
    const int idx = blk;                   // 40 x 64
    k0 = (idx % 40) * 64; n0 = (idx / 40) * 64;
    dstK = 2560; dst = wqkv_t;
    if (n0 < 2048)      { src = wq; col = n0;        srcN = 2048; }
    else if (n0 < 3072) { src = wk; col = n0 - 2048; srcN = 1024; }
    else                { src = wv; col = n0 - 3072; srcN = 1024; }
  } else {
    const int idx = blk - 2560;            // 32 x 40
    k0 = (idx & 31) * 64; n0 = (idx >> 5) * 64;
    dstK = 2048; dst = wo_t; src = wo; col = n0; srcN = 2560;
  }
  {
    const int rf = tid >> 4, c4 = (tid & 15) * 4;
#pragma unroll
    for (int i = 0; i < 4; ++i) {  // 16 rows per iter, 256B contiguous per row
      const int r = i * 16 + rf;
      const f32x4 v = __builtin_nontemporal_load(
          (const f32x4*)(src + (long)(k0 + r) * srcN + col + c4));
      tile[r][c4] = v.x; tile[r][c4 + 1] = v.y;
      tile[r][c4 + 2] = v.z; tile[r][c4 + 3] = v.w;
    }
  }
  __syncthreads();
  {
    const int nf = tid >> 3, kcq = (tid & 7) * 8;
#pragma unroll
    for (int i = 0; i < 2; ++i) {  // 32 dst rows per iter, 128B/row
      const int nn = i * 32 + nf;
      bf16x8 o8;
#pragma unroll
      for (int j = 0; j < 8; ++j) o8[j] = (bf16)tile[kcq + j][nn];
      *(bf16x8*)(dst + (long)(n0 + nn) * dstK + k0 + kcq) = o8;
    }
  }
}

// ---------------- pure streaming phase: cache copy + x cvt ------------------
// blocks [0,2048):    cache copy, 16 rows/block, 4 rows/wave, nt both ways,
//                     v stream staggered by s^2048 to decorrelate channels.
// blocks [2048,4608): x f32->bf16, 2 float4 per thread, nt loads.
__global__ __launch_bounds__(256) void stream_kernel(
    const float* __restrict__ kc, const float* __restrict__ vc,
    float* __restrict__ kout, float* __restrict__ vout,
    const int* __restrict__ p_ci, const float* __restrict__ x,
    bf16* __restrict__ xb) {
  const int blk = blockIdx.x;
  const int tid = threadIdx.x;
  if (blk >= 2048) {  // ---- x f32 -> bf16 ----
    const long i = (long)(blk - 2048) * 512 + tid;
    const f32x4 v0 = __builtin_nontemporal_load((const f32x4*)x + i);
    const f32x4 v1 = __builtin_nontemporal_load((const f32x4*)x + i + 256);
    bf16x4 o0, o1;
    o0.x = (bf16)v0.x; o0.y = (bf16)v0.y; o0.z = (bf16)v0.z; o0.w = (bf16)v0.w;
    o1.x = (bf16)v1.x; o1.y = (bf16)v1.y; o1.z = (bf16)v1.z; o1.w = (bf16)v1.w;
    ((bf16x4*)xb)[i] = o0;
    ((bf16x4*)xb)[i + 256] = o1;
    return;
  }
  // ---- cache copy ----
  const int cb = blk;              // 0..2047
  const int bk = cb >> 8;          // 0..7
  const int s0 = (cb & 255) * 16 + (tid >> 6) * 4;
  const int l = tid & 63;
  const int ci = *p_ci;
  f32x4 kr[4], vr[4];
#pragma unroll
  for (int i = 0; i < 4; ++i) {  // all loads issued first: 8 in flight
    const int sk = s0 + i;
    const int sv = sk ^ 2048;    // bijective stagger: decorrelate k/v streams
    if ((unsigned)(sk - ci) >= 1024u)
      kr[i] = __builtin_nontemporal_load((const f32x4*)kc +
                                         ((long)bk * 4096 + sk) * 64 + l);
    if ((unsigned)(sv - ci) >= 1024u)
      vr[i] = __builtin_nontemporal_load((const f32x4*)vc +
                                         ((long)bk * 4096 + sv) * 64 + l);
  }
#pragma unroll
  for (int i = 0; i < 4; ++i) {
    const int sk = s0 + i;
    const int sv = sk ^ 2048;
    if ((unsigned)(sk - ci) >= 1024u)
      __builtin_nontemporal_store(kr[i], (f32x4*)kout +
                                  ((long)bk * 4096 + sk) * 64 + l);
    if ((unsigned)(sv - ci) >= 1024u)
      __builtin_nontemporal_store(vr[i], (f32x4*)vout +
                                  ((long)bk * 4096 + sv) * 64 + l);
  }
}

// ---------------- V path: qkv slice -> vout (f32 scatter) + vt bf16 [d][s] ----
__global__ __launch_bounds__(256) void v_trans_kernel(const bf16* __restrict__ qkv,
                                                      const int* __restrict__ p_ci,
                                                      float* __restrict__ vout,
                                                      bf16* __restrict__ vt) {
  __shared__ float tile[32][33];
  const int s0 = blockIdx.x * 32, d0 = blockIdx.y * 32, bk = blockIdx.z;
  const int b = bk >> 2, kvh = bk & 3;
  const int ci = *p_ci;
  const int tx = threadIdx.x, ty = threadIdx.y;
#pragma unroll
  for (int i = 0; i < 4; ++i) {
    const int s = s0 + ty + i * 8;
    const float val =
        (float)qkv[(long)(b * 1024 + s) * 4096 + (12 + kvh) * 256 + d0 + tx];
    tile[ty + i * 8][tx] = val;
    vout[((long)bk * 4096 + ci + s) * 256 + d0 + tx] = val;
  }
  __syncthreads();
  bf16* dstb = vt + ((long)bk * 256 + d0) * 1024 + s0;
#pragma unroll
  for (int i = 0; i < 4; ++i)
    dstb[(long)(ty + i * 8) * 1024 + tx] = (bf16)tile[tx][ty + i * 8];
}

// ---------------- bf16 MFMA GEMM: C(MxN) = A(MxK) * BT(NxK)^T ----------------
// BK=32, LDS double-buffer with COUNTED vmcnt (attn-style): prefetch of tile
// k+1 issued first, s_waitcnt vmcnt(VMC) waits only for tile k's per-wave
// loads, prefetch stays in flight across the raw s_barrier. Two barriers per
// K-step; NT=512 gives 8 waves/block (4 waves/SIMD at 2 blocks/CU).
template <int BM, int BN, int K, int N, int NT, typename OutT>
__global__ __launch_bounds__(NT) void gemm_kernel(const bf16* __restrict__ A,
                                                  const bf16* __restrict__ BT,
                                                  OutT* __restrict__ C) {
  __shared__ bf16 As[2 * BM * 32];
  __shared__ bf16 Bs[2 * BN * 32];
  constexpr int NW = NT / 64;
  constexpr int WGM = 2, WGN = NW / 2;
  constexpr int WM = BM / WGM, WN = BN / WGN;
  constexpr int MI = WM / 16, NI = WN / 16;
  constexpr int VMC = (BM + BN) * 4 / NT;  // per-wave GLLs per stage
  static_assert((BM * 4) % NT == 0 && (BN * 4) % NT == 0, "stage tiling");
  const int bm = blockIdx.x, bn = blockIdx.y;
  const int tid = threadIdx.x;
  const int wave = tid >> 6, lane = tid & 63;
  const int quad = lane >> 4, l16 = lane & 15;
  const int wm = (wave % WGM) * WM, wn = (wave / WGM) * WN;
  f32x4 acc[MI][NI] = {};
  const int srow = tid >> 2;   // [0, NT/4)
  const int sslot = tid & 3;
  const bf16* Ag = A + (long)(bm * BM) * K;
  const bf16* Bg = BT + (long)(bn * BN) * K;
  auto stage = [&](int buf, int k0) {
#pragma unroll
    for (int i = 0; i < BM * 4 / NT; ++i) {
      const int r = i * (NT / 4) + srow;
      const int cc = (sslot - (r >> 1)) & 3;
      GLL(As + buf * BM * 32 + (i * NT + wave * 64) * 8,
          Ag + (long)r * K + k0 + cc * 8);
    }
#pragma unroll
    for (int i = 0; i < BN * 4 / NT; ++i) {
      const int r = i * (NT / 4) + srow;
      const int cc = (sslot - (r >> 1)) & 3;
      GLL(Bs + buf * BN * 32 + (i * NT + wave * 64) * 8,
          Bg + (long)r * K + k0 + cc * 8);
    }
  };
  stage(0, 0);
  int buf = 0;
  for (int k0 = 0; k0 < K; k0 += 32) {
    if (k0 + 32 < K) {
      stage(buf ^ 1, k0 + 32);  // prefetch next tile into other buffer
      waitcnt_vm<VMC>();        // wait only for CURRENT tile's per-wave loads
    } else {
      waitcnt_vm<0>();
    }
    __builtin_amdgcn_s_barrier();  // all waves' current-tile loads landed
    asm volatile("" ::: "memory");
    const bf16* Ab = As + buf * BM * 32;
    const bf16* Bb = Bs + buf * BN * 32;
    bf16x8 af[MI], bfr[NI];
#pragma unroll
    for (int mi = 0; mi < MI; ++mi) {
      const int r = wm + mi * 16 + l16;
      af[mi] = *(const bf16x8*)(Ab + r * 32 + (((quad + (r >> 1)) & 3) * 8));
    }
#pragma unroll
    for (int ni = 0; ni < NI; ++ni) {
      const int r = wn + ni * 16 + l16;
      bfr[ni] = *(const bf16x8*)(Bb + r * 32 + (((quad + (r >> 1)) & 3) * 8));
    }
#pragma unroll
    for (int mi = 0; mi < MI; ++mi)
#pragma unroll
      for (int ni = 0; ni < NI; ++ni)
        acc[mi][ni] = MFMA16(af[mi], bfr[ni], acc[mi][ni]);
    // this wave's ds_reads completed (lgkmcnt before MFMA use); barrier makes
    // it safe for next iter's GLLs to overwrite buf.
    asm volatile("" ::: "memory");
    __builtin_amdgcn_s_barrier();
    buf ^= 1;
  }
  const int crow = bm * BM + wm + quad * 4;
  const int ccol = bn * BN + wn + l16;
#pragma unroll
  for (int mi = 0; mi < MI; ++mi)
#pragma unroll
    for (int ni = 0; ni < NI; ++ni)
#pragma unroll
      for (int r = 0; r < 4; ++r)
        C[(long)(crow + mi * 16 + r) * N + ccol + ni * 16] = (OutT)acc[mi][ni][r];
}

// ---------------- RMSNorm + RoPE (q,k only; fast HW sin/cos) ----------------
// One block per (b,t): 384 threads = 6 waves, wave handles 2 slots (rows).
// bf16x8 vector loads; 32-lane shfl reduction; RoPE partner (d +- 128) via
// __shfl_xor(.,16). No LDS, no barriers.
__global__ __launch_bounds__(384) void normrope_kernel(
    const bf16* __restrict__ qkv, const float* __restrict__ qw,
    const float* __restrict__ kw, const int* __restrict__ p_pos,
    const int* __restrict__ p_ci, float* __restrict__ kout,
    bf16* __restrict__ q_bf, bf16* __restrict__ k_bf) {
  const int bt = blockIdx.x;           // 0..2047
  const int t = bt & 1023, b = bt >> 10;
  const int wave = threadIdx.x >> 6;   // 0..5
  const int lane = threadIdx.x & 63;
  const int half = lane >> 5;          // wave's 2 rows
  const int l32 = lane & 31;
  const int slot = wave * 2 + half;    // 0..11 (0..7 q, 8..11 k) wave-uniform q/k
  const int d0 = l32 * 8;
  const bf16x8 v8 = *(const bf16x8*)(qkv + (long)bt * 4096 + slot * 256 + d0);
  float v[8], ss = 0.0f;
#pragma unroll
  for (int j = 0; j < 8; ++j) {
    v[j] = (float)v8[j];
    ss += v[j] * v[j];
  }
#pragma unroll
  for (int i = 1; i < 32; i <<= 1) ss += __shfl_xor(ss, i);  // 32-lane row sum
  const float rstd = rsqrtf(ss * (1.0f / 256.0f) + 1e-6f);
  const bool isq = slot < 8;
  const float* wp = isq ? qw : kw;
  const float4 w0 = *(const float4*)(wp + d0);
  const float4 w1 = *(const float4*)(wp + d0 + 4);
  float nv[8];
  nv[0] = v[0] * rstd * (1.0f + w0.x); nv[1] = v[1] * rstd * (1.0f + w0.y);
  nv[2] = v[2] * rstd * (1.0f + w0.z); nv[3] = v[3] * rstd * (1.0f + w0.w);
  nv[4] = v[4] * rstd * (1.0f + w1.x); nv[5] = v[5] * rstd * (1.0f + w1.y);
  nv[6] = v[6] * rstd * (1.0f + w1.z); nv[7] = v[7] * rstd * (1.0f + w1.w);
  float pv[8];
#pragma unroll
  for (int j = 0; j < 8; ++j) pv[j] = __shfl_xor(nv[j], 16);  // partner d +- 128
  const float pt = (float)(*p_pos + t);
  const int e0 = (l32 & 15) * 8;  // d0 mod 128
  float outv[8];
#pragma unroll
  for (int j = 0; j < 8; ++j) {
    const float inv_freq = exp2f((float)(e0 + j) * -0.10381025296522976f);
    // v_sin/v_cos take REVOLUTIONS; fract reduction. err ~2e-4 << bf16 eps.
    float rev = pt * inv_freq * 0.15915494309189535f;
    rev = rev - floorf(rev);
    const float sn = __builtin_amdgcn_sinf(rev);
    const float cs = __builtin_amdgcn_cosf(rev);
    outv[j] = (d0 < 128) ? nv[j] * cs - pv[j] * sn : nv[j] * cs + pv[j] * sn;
  }
  bf16x8 ob;
#pragma unroll
  for (int j = 0; j < 8; ++j) ob[j] = (bf16)outv[j];
  if (isq) {
    *(bf16x8*)(q_bf + ((long)(b * 8 + slot) * 1024 + t) * 256 + d0) = ob;
  } else {
    const int kh = slot - 8;
    const int ci = *p_ci;
    *(bf16x8*)(k_bf + ((long)(b * 4 + kh) * 1024 + t) * 256 + d0) = ob;
    float4 f0, f1;
    f0.x = outv[0]; f0.y = outv[1]; f0.z = outv[2]; f0.w = outv[3];
    f1.x = outv[4]; f1.y = outv[5]; f1.z = outv[6]; f1.w = outv[7];
    float* kg = kout + ((long)(b * 4 + kh) * 4096 + ci + t) * 256 + d0;
    *(float4*)(kg) = f0;
    *(float4*)(kg + 4) = f1;
  }
}

// ---------------- flash attention over the T new tokens (all valid, no mask) ----
// Double-buffered K/V tiles with COUNTED vmcnt: prefetch of step st+1 is
// issued first, then s_waitcnt vmcnt(16) waits only for step st's 16 loads
// (prefetch stays in flight across the raw s_barrier). 1 block/CU, so all
// latency hiding must come from this in-wave ILP.
__global__ __launch_bounds__(256) void attn_kernel(const bf16* __restrict__ q_bf,
                                                   const bf16* __restrict__ k_bf,
                                                   const bf16* __restrict__ vt_bf,
                                                   bf16* __restrict__ attn) {
  __shared__ bf16 Ks[2][64 * 256];   // [s][d], chunk-swizzled
  __shared__ bf16 Vs[2][256 * 64];   // [d][s], chunk-swizzled
  __shared__ bf16 Ps[64 * 72];       // [t][s], +8 pad (VALU-written)
  const int qt = blockIdx.x, h = blockIdx.y, b = blockIdx.z;
  const int kvh = h >> 1;
  const int tid = threadIdx.x;
  const int wave = tid >> 6, lane = tid & 63, quad = lane >> 4, l16 = lane & 15;
  bf16x8 qf[8];
  const bf16* qg =
      q_bf + ((long)(b * 8 + h) * 1024 + qt * 64 + wave * 16 + l16) * 256 + quad * 8;
#pragma unroll
  for (int i = 0; i < 8; ++i) qf[i] = *(const bf16x8*)(qg + i * 32);
  f32x4 o[16] = {};
  float m_r[4] = {-1e30f, -1e30f, -1e30f, -1e30f};
  float l_r[4] = {0.f, 0.f, 0.f, 0.f};
  const float sfac = 0.0625f * 1.44269504088896f;  // SCALE * log2(e)
  const bf16* kgb = k_bf + (long)(b * 4 + kvh) * 1024 * 256;
  const bf16* vgb = vt_bf + (long)(b * 4 + kvh) * 256 * 1024;
  const int krow = tid >> 5, kccp = tid & 31;
  const int kcc = kccp ^ (krow & 7);
  const int vrow0 = tid >> 3, vccp = tid & 7;
  // per-wave: 8 K GLLs + 8 V GLLs = 16 VMEM ops per stage
  auto stage = [&](int sb, int st) {
#pragma unroll
    for (int i = 0; i < 8; ++i) {  // K tile 64x256
      GLL(&Ks[sb][(i * 256 + wave * 64) * 8],
          kgb + (long)(st * 64 + krow + i * 8) * 256 + kcc * 8);
    }
#pragma unroll
    for (int i = 0; i < 8; ++i) {  // V^T tile 256x64
      const int vr = vrow0 + i * 32;
      GLL(&Vs[sb][(i * 256 + wave * 64) * 8],
          vgb + (long)vr * 1024 + st * 64 + (vccp ^ (vr & 7)) * 8);
    }
  };
  stage(0, 0);
  int sb = 0;
  for (int st = 0; st < 16; ++st) {
    if (st < 15) {
      stage(sb ^ 1, st + 1);  // prefetch next tile into other buffer
      // wait only for CURRENT tile's 16 loads; prefetch (16) stays in flight
      asm volatile("s_waitcnt vmcnt(16)" ::: "memory");
    } else {
      asm volatile("s_waitcnt vmcnt(0)" ::: "memory");
    }
    __builtin_amdgcn_s_barrier();  // all waves' current-tile loads landed
    const bf16* Kb = Ks[sb];
    const bf16* Vb = Vs[sb];
    f32x4 sacc[4] = {};
#pragma unroll
    for (int kk = 0; kk < 8; ++kk) {
#pragma unroll
      for (int ni = 0; ni < 4; ++ni) {
        const int r = ni * 16 + l16;
        bf16x8 kf = *(const bf16x8*)(Kb + r * 256 + (((kk * 4 + quad) ^ (r & 7)) * 8));
        sacc[ni] = MFMA16(qf[kk], kf, sacc[ni]);
      }
    }
    float alpha_r[4];
#pragma unroll
    for (int r = 0; r < 4; ++r) {
      float s0 = sacc[0][r] * sfac, s1 = sacc[1][r] * sfac;
      float s2 = sacc[2][r] * sfac, s3 = sacc[3][r] * sfac;
      float mx = fmaxf(fmaxf(s0, s1), fmaxf(s2, s3));
#pragma unroll
      for (int dd = 1; dd < 16; dd <<= 1) mx = fmaxf(mx, __shfl_xor(mx, dd));
      float mnew = fmaxf(m_r[r], mx);
      float al = exp2f(m_r[r] - mnew);
      m_r[r] = mnew;
      alpha_r[r] = al;
      float p0 = exp2f(s0 - mnew), p1 = exp2f(s1 - mnew);
      float p2 = exp2f(s2 - mnew), p3 = exp2f(s3 - mnew);
      float rs = p0 + p1 + p2 + p3;
#pragma unroll
      for (int dd = 1; dd < 16; dd <<= 1) rs += __shfl_xor(rs, dd);
      l_r[r] = l_r[r] * al + rs;
      const int prow = (wave * 16 + quad * 4 + r) * 72;
      Ps[prow + l16] = (bf16)p0;
      Ps[prow + 16 + l16] = (bf16)p1;
      Ps[prow + 32 + l16] = (bf16)p2;
      Ps[prow + 48 + l16] = (bf16)p3;
    }
#pragma unroll
    for (int n2 = 0; n2 < 16; ++n2) {
      f32x4 tv = o[n2];
      tv.x *= alpha_r[0]; tv.y *= alpha_r[1]; tv.z *= alpha_r[2]; tv.w *= alpha_r[3];
      o[n2] = tv;
    }
    // NOTE: no barrier here. Ps rows [wave*16, wave*16+16) are written and
    // read ONLY by this wave; in-wave ds ordering (compiler lgkmcnt) suffices.
    bf16x8 pf0 = *(const bf16x8*)(Ps + (wave * 16 + l16) * 72 + quad * 8);
    bf16x8 pf1 = *(const bf16x8*)(Ps + (wave * 16 + l16) * 72 + 32 + quad * 8);
#pragma unroll
    for (int n2 = 0; n2 < 16; ++n2) {
      const int r = n2 * 16 + l16;
      bf16x8 vf0 = *(const bf16x8*)(Vb + r * 64 + ((quad ^ (r & 7)) * 8));
      o[n2] = MFMA16(pf0, vf0, o[n2]);
      bf16x8 vf1 = *(const bf16x8*)(Vb + r * 64 + (((4 + quad) ^ (r & 7)) * 8));
      o[n2] = MFMA16(pf1, vf1, o[n2]);
    }
    // all ds_reads of buffer sb were consumed by MFMAs above (lgkmcnt waited),
    // so after this barrier it is safe for next iter to overwrite sb.
    __builtin_amdgcn_s_barrier();
    sb ^= 1;
  }
  float inv_l[4];
#pragma unroll
  for (int r = 0; r < 4; ++r) inv_l[r] = 1.0f / l_r[r];
  bf16* og = attn + ((long)(b * 1024 + qt * 64 + wave * 16 + quad * 4)) * 2048 +
             h * 256 + l16;
#pragma unroll
  for (int n2 = 0; n2 < 16; ++n2)
#pragma unroll
    for (int r = 0; r < 4; ++r)
      og[(long)r * 2048 + n2 * 16] = (bf16)(o[n2][r] * inv_l[r]);
}

extern "C" void kernel_launch(void* const* d_in, const int* in_sizes, int n_in,
                              void* d_out, int out_size, void* d_ws, size_t ws_size,
                              hipStream_t stream) {
  const float* x = (const float*)d_in[0];
  const float* k_cache = (const float*)d_in[1];
  const float* v_cache = (const float*)d_in[2];
  const float* wq = (const float*)d_in[3];
  const float* wk = (const float*)d_in[4];
  const float* wv = (const float*)d_in[5];
  const float* wo = (const float*)d_in[6];
  const float* qnw = (const float*)d_in[7];
  const float* knw = (const float*)d_in[8];
  const int* p_pos = (const int*)d_in[9];
  const int* p_ci = (const int*)d_in[10];

  float* out0 = (float*)d_out;                    // (2,1024,2560)
  float* kout = out0 + (long)2 * 1024 * 2560;     // (2,4,4096,256)
  float* vout = kout + (long)2 * 4 * 4096 * 256;  // (2,4,4096,256)

  char* w = (char*)d_ws;
  bf16* x_bf = (bf16*)(w);                  // 2048x2560 bf16        10,485,760 B
  bf16* wqkv_t = (bf16*)(w + 10485760);     // 4096x2560 bf16        20,971,520 B
  bf16* wo_t = (bf16*)(w + 31457280);       // 2560x2048 bf16        10,485,760 B
  bf16* qkv = (bf16*)(w + 41943040);        // 2048x4096 bf16        16,777,216 B
  bf16* q_bf = (bf16*)(w + 58720256);       // (2,8,1024,256) bf16    8,388,608 B
  bf16* k_bf = (bf16*)(w + 67108864);       // (2,4,1024,256) bf16    4,194,304 B
  bf16* vt_bf = (bf16*)(w + 71303168);      // (2,4,256,1024) bf16    4,194,304 B
  bf16* attn_b = (bf16*)(w + 75497472);     // 2048x2048 bf16         8,388,608 B

  // 1a. weight transposes (LDS phase, isolated dispatch for attribution)
  trans_kernel<<<3840, 256, 0, stream>>>(wq, wk, wv, wqkv_t, wo, wo_t);

  // 1b. pure streaming: cache copy (nt, staggered) + x f32->bf16
  stream_kernel<<<4608, 256, 0, stream>>>(k_cache, v_cache, kout, vout, p_ci,
                                          x, x_bf);

  // 2. fused QKV projection — 128x128 counted-vmcnt dbuf, 512 thr (8 waves)
  gemm_kernel<128, 128, 2560, 4096, 512, bf16>
      <<<dim3(16, 32), 512, 0, stream>>>(x_bf, wqkv_t, qkv);

  // 3a. V path straight from qkv: vout f32 scatter + vt bf16 transpose
  dim3 tb(32, 8);
  v_trans_kernel<<<dim3(32, 8, 8), tb, 0, stream>>>(qkv, p_ci, vout, vt_bf);

  // 3b. rmsnorm + rope for q,k — vectorized, no LDS/barriers
  normrope_kernel<<<2048, 384, 0, stream>>>(qkv, qnw, knw, p_pos, p_ci,
                                            kout, q_bf, k_bf);

  // 4. attention (double-buffered, counted vmcnt)
  attn_kernel<<<dim3(16, 8, 2), 256, 0, stream>>>(q_bf, k_bf, vt_bf, attn_b);

  // 5. output projection — 64x128 counted-vmcnt dbuf, 256 thr
  gemm_kernel<64, 128, 2048, 2560, 256, float>
      <<<dim3(32, 20), 256, 0, stream>>>(attn_b, wo_t, out0);
}